// Round 1
// baseline (8194.346 us; speedup 1.0000x reference)
//
#include <hip/hip_runtime.h>
#include <math.h>

#define TT   256
#define DD   2048
#define VV   32000
#define NBLK 4
#define CC   512
#define RR   32
#define MTT  3
#define NBAT 2
#define NTOK 512   // NBAT*TT

__device__ __forceinline__ float sigm(float x){ return 1.0f/(1.0f+expf(-x)); }

__device__ __forceinline__ float block_sum256(float v){
  #pragma unroll
  for (int off = 32; off > 0; off >>= 1) v += __shfl_down(v, off);
  __shared__ float sh[4];
  __syncthreads();
  if ((threadIdx.x & 63) == 0) sh[threadIdx.x >> 6] = v;
  __syncthreads();
  return sh[0] + sh[1] + sh[2] + sh[3];
}

// out[row,d] = alpha_row * sgn0(w[row,d]),  alpha_row = mean_d |w[row,d]|  (sgn0(0)=+1)
__global__ __launch_bounds__(256) void rowsign_kernel(const float* __restrict__ w_,
                                                      float* __restrict__ out){
  size_t row = blockIdx.x;
  const float* w = w_ + row * DD;
  float* o = out + row * DD;
  float s = 0.f;
  #pragma unroll
  for (int j = 0; j < 8; j++) s += fabsf(w[threadIdx.x + j*256]);
  float a = block_sum256(s) * (1.f/DD);
  #pragma unroll
  for (int j = 0; j < 8; j++){
    int d = threadIdx.x + j*256;
    o[d] = (w[d] < 0.f) ? -a : a;
  }
}

// sqk[d] = (mean|q|)(mean|k|) * sgn0(q[d]) * sgn0(k[d])   (per block i)
__global__ __launch_bounds__(256) void svec_pair_kernel(const float* __restrict__ q_,
    const float* __restrict__ k_, float* __restrict__ out_){
  size_t i = blockIdx.x;
  const float* q = q_ + i * DD;
  const float* k = k_ + i * DD;
  float* o = out_ + i * DD;
  float sq = 0.f, sk = 0.f;
  #pragma unroll
  for (int j = 0; j < 8; j++){
    int d = threadIdx.x + j*256;
    sq += fabsf(q[d]); sk += fabsf(k[d]);
  }
  float aq = block_sum256(sq) * (1.f/DD);
  float ak = block_sum256(sk) * (1.f/DD);
  float a2 = aq * ak;
  #pragma unroll
  for (int j = 0; j < 8; j++){
    int d = threadIdx.x + j*256;
    o[d] = ((q[d] < 0.f) != (k[d] < 0.f)) ? -a2 : a2;
  }
}

// tokens: gather codebook row, ste_sign per token row, cyclic shift by t
__global__ __launch_bounds__(256) void encode_kernel(const int* __restrict__ idx,
    const float* __restrict__ cb, float* __restrict__ X){
  int token = blockIdx.x;
  int t = token & (TT - 1);
  size_t row = (size_t)idx[token] * DD;
  float s = 0.f;
  #pragma unroll
  for (int j = 0; j < 8; j++) s += fabsf(cb[row + threadIdx.x + j*256]);
  float a = block_sum256(s) * (1.f/DD);
  #pragma unroll
  for (int j = 0; j < 8; j++){
    int d = threadIdx.x + j*256;
    float w = cb[row + ((d - t) & (DD - 1))];
    X[(size_t)token * DD + d] = (w < 0.f) ? -a : a;
  }
}

// mem[t] = x[t] + decay*mem[t-1], per (b,d) column
__global__ __launch_bounds__(256) void ema_kernel(const float* __restrict__ X,
    float* __restrict__ M, const float* __restrict__ dlogit){
  int d = blockIdx.x * 256 + threadIdx.x;
  size_t base = (size_t)blockIdx.y * TT * DD + d;
  float decay = sigm(*dlogit);
  float m = 0.f;
  #pragma unroll 4
  for (int t = 0; t < TT; t++){
    m = fmaf(decay, m, X[base + (size_t)t * DD]);
    M[base + (size_t)t * DD] = m;
  }
}

// mode 0: pre=a; mode 1: pre=a+b; mode 2: pre=a*(1+gate*(b-1)), gate=sigmoid(*gate_ptr)
// out = LN(pre)*g + be (+ pos)
__global__ __launch_bounds__(256) void ln_kernel(const float* __restrict__ A,
    const float* __restrict__ Bb, const float* __restrict__ g, const float* __restrict__ be,
    const float* __restrict__ pos, const float* __restrict__ gate_ptr,
    float* __restrict__ out, int mode){
  size_t row = blockIdx.x;
  const float* a = A + row * DD;
  const float* bb = Bb ? Bb + row * DD : nullptr;
  float gate = (mode == 2) ? sigm(*gate_ptr) : 0.f;
  float vals[8]; float s = 0.f, ss = 0.f;
  #pragma unroll
  for (int j = 0; j < 8; j++){
    int d = threadIdx.x + j*256;
    float v = a[d];
    if (mode == 1) v += bb[d];
    else if (mode == 2) v = v * (1.f + gate * (bb[d] - 1.f));
    vals[j] = v; s += v; ss += v*v;
  }
  float mean = block_sum256(s) * (1.f/DD);
  float var  = block_sum256(ss) * (1.f/DD) - mean*mean;
  float inv  = rsqrtf(var + 1e-5f);
  float* o = out + row * DD;
  #pragma unroll
  for (int j = 0; j < 8; j++){
    int d = threadIdx.x + j*256;
    float y = (vals[j] - mean) * inv * g[d] + be[d];
    if (pos) y += pos[d];
    o[d] = y;
  }
}

// C[M,N] = act( (A[M,K] . B[N,K]^T  with per-k scale) * alpha + bias[n] ) (+res)
// ACT: 0 none, 1 sigmoid(4v), 2 exact gelu. CAUSAL: zero where n>m (after act).
template<int ACT, bool CAUSAL>
__global__ __launch_bounds__(256) void mm_nt_kernel(
    const float* __restrict__ A, const float* __restrict__ Bm, float* __restrict__ Cm,
    int M, int N, int K, int lda, int ldb, int ldc,
    long sA, long sB, long sC,
    const float* __restrict__ kscale, const float* __restrict__ bias,
    const float* __restrict__ res, const float* __restrict__ alpha_ptr, float alpha_c)
{
  A  += (size_t)blockIdx.z * sA;
  Bm += (size_t)blockIdx.z * sB;
  Cm += (size_t)blockIdx.z * sC;
  __shared__ float As[16][68];
  __shared__ float Bs[16][68];
  const int tid = threadIdx.x;
  const int row0 = blockIdx.y << 6, col0 = blockIdx.x << 6;
  const int lm = tid >> 2, lk = (tid & 3) << 2;
  const int ty4 = (tid >> 4) << 2, tx4 = (tid & 15) << 2;
  float acc[4][4] = {};
  for (int kt = 0; kt < K; kt += 16){
    float av0=0,av1=0,av2=0,av3=0;
    int m = row0 + lm;
    if (m < M){
      const float4 t4 = *reinterpret_cast<const float4*>(A + (size_t)m * lda + kt + lk);
      av0=t4.x; av1=t4.y; av2=t4.z; av3=t4.w;
      if (kscale){
        const float4 ks = *reinterpret_cast<const float4*>(kscale + kt + lk);
        av0*=ks.x; av1*=ks.y; av2*=ks.z; av3*=ks.w;
      }
    }
    As[lk+0][lm]=av0; As[lk+1][lm]=av1; As[lk+2][lm]=av2; As[lk+3][lm]=av3;
    float bv0=0,bv1=0,bv2=0,bv3=0;
    int n = col0 + lm;
    if (n < N){
      const float4 t4 = *reinterpret_cast<const float4*>(Bm + (size_t)n * ldb + kt + lk);
      bv0=t4.x; bv1=t4.y; bv2=t4.z; bv3=t4.w;
    }
    Bs[lk+0][lm]=bv0; Bs[lk+1][lm]=bv1; Bs[lk+2][lm]=bv2; Bs[lk+3][lm]=bv3;
    __syncthreads();
    #pragma unroll
    for (int k = 0; k < 16; k++){
      const float a0=As[k][ty4+0], a1=As[k][ty4+1], a2=As[k][ty4+2], a3=As[k][ty4+3];
      const float b0=Bs[k][tx4+0], b1=Bs[k][tx4+1], b2=Bs[k][tx4+2], b3=Bs[k][tx4+3];
      acc[0][0]=fmaf(a0,b0,acc[0][0]); acc[0][1]=fmaf(a0,b1,acc[0][1]);
      acc[0][2]=fmaf(a0,b2,acc[0][2]); acc[0][3]=fmaf(a0,b3,acc[0][3]);
      acc[1][0]=fmaf(a1,b0,acc[1][0]); acc[1][1]=fmaf(a1,b1,acc[1][1]);
      acc[1][2]=fmaf(a1,b2,acc[1][2]); acc[1][3]=fmaf(a1,b3,acc[1][3]);
      acc[2][0]=fmaf(a2,b0,acc[2][0]); acc[2][1]=fmaf(a2,b1,acc[2][1]);
      acc[2][2]=fmaf(a2,b2,acc[2][2]); acc[2][3]=fmaf(a2,b3,acc[2][3]);
      acc[3][0]=fmaf(a3,b0,acc[3][0]); acc[3][1]=fmaf(a3,b1,acc[3][1]);
      acc[3][2]=fmaf(a3,b2,acc[3][2]); acc[3][3]=fmaf(a3,b3,acc[3][3]);
    }
    __syncthreads();
  }
  float alpha = alpha_c * (alpha_ptr ? *alpha_ptr : 1.f);
  #pragma unroll
  for (int i = 0; i < 4; i++){
    int m = row0 + ty4 + i;
    if (m >= M) continue;
    #pragma unroll
    for (int j = 0; j < 4; j++){
      int n = col0 + tx4 + j;
      if (n >= N) continue;
      float v = acc[i][j] * alpha;
      if (bias) v += bias[n];
      if (ACT == 1) v = sigm(4.f * v);
      else if (ACT == 2) v = 0.5f * v * (1.f + erff(v * 0.70710678118654752f));
      if (CAUSAL && n > m) v = 0.f;
      if (res) v += res[(size_t)m * ldc + n];
      Cm[(size_t)m * ldc + n] = v;
    }
  }
}

// C[M,N] = (A[M,K] . B[K,N]) * colscale[n]
__global__ __launch_bounds__(256) void mm_nn_kernel(
    const float* __restrict__ A, const float* __restrict__ Bm, float* __restrict__ Cm,
    int M, int N, int K, int lda, int ldb, int ldc,
    long sA, long sB, long sC,
    const float* __restrict__ colscale)
{
  A  += (size_t)blockIdx.z * sA;
  Bm += (size_t)blockIdx.z * sB;
  Cm += (size_t)blockIdx.z * sC;
  __shared__ float As[16][68];
  __shared__ float Bs[16][68];
  const int tid = threadIdx.x;
  const int row0 = blockIdx.y << 6, col0 = blockIdx.x << 6;
  const int lm = tid >> 2, lk = (tid & 3) << 2;
  const int kb = tid >> 4, nb = (tid & 15) << 2;
  const int ty4 = (tid >> 4) << 2, tx4 = (tid & 15) << 2;
  float acc[4][4] = {};
  for (int kt = 0; kt < K; kt += 16){
    float av0=0,av1=0,av2=0,av3=0;
    int m = row0 + lm;
    if (m < M){
      const float4 t4 = *reinterpret_cast<const float4*>(A + (size_t)m * lda + kt + lk);
      av0=t4.x; av1=t4.y; av2=t4.z; av3=t4.w;
    }
    As[lk+0][lm]=av0; As[lk+1][lm]=av1; As[lk+2][lm]=av2; As[lk+3][lm]=av3;
    float bv0=0,bv1=0,bv2=0,bv3=0;
    int n = col0 + nb;
    if (n < N && kt + kb < K){
      const float4 t4 = *reinterpret_cast<const float4*>(Bm + (size_t)(kt + kb) * ldb + n);
      bv0=t4.x; bv1=t4.y; bv2=t4.z; bv3=t4.w;
    }
    Bs[kb][nb+0]=bv0; Bs[kb][nb+1]=bv1; Bs[kb][nb+2]=bv2; Bs[kb][nb+3]=bv3;
    __syncthreads();
    #pragma unroll
    for (int k = 0; k < 16; k++){
      const float a0=As[k][ty4+0], a1=As[k][ty4+1], a2=As[k][ty4+2], a3=As[k][ty4+3];
      const float b0=Bs[k][tx4+0], b1=Bs[k][tx4+1], b2=Bs[k][tx4+2], b3=Bs[k][tx4+3];
      acc[0][0]=fmaf(a0,b0,acc[0][0]); acc[0][1]=fmaf(a0,b1,acc[0][1]);
      acc[0][2]=fmaf(a0,b2,acc[0][2]); acc[0][3]=fmaf(a0,b3,acc[0][3]);
      acc[1][0]=fmaf(a1,b0,acc[1][0]); acc[1][1]=fmaf(a1,b1,acc[1][1]);
      acc[1][2]=fmaf(a1,b2,acc[1][2]); acc[1][3]=fmaf(a1,b3,acc[1][3]);
      acc[2][0]=fmaf(a2,b0,acc[2][0]); acc[2][1]=fmaf(a2,b1,acc[2][1]);
      acc[2][2]=fmaf(a2,b2,acc[2][2]); acc[2][3]=fmaf(a2,b3,acc[2][3]);
      acc[3][0]=fmaf(a3,b0,acc[3][0]); acc[3][1]=fmaf(a3,b1,acc[3][1]);
      acc[3][2]=fmaf(a3,b2,acc[3][2]); acc[3][3]=fmaf(a3,b3,acc[3][3]);
    }
    __syncthreads();
  }
  #pragma unroll
  for (int i = 0; i < 4; i++){
    int m = row0 + ty4 + i;
    if (m >= M) continue;
    #pragma unroll
    for (int j = 0; j < 4; j++){
      int n = col0 + tx4 + j;
      if (n >= N) continue;
      float v = acc[i][j];
      if (colscale) v *= colscale[n];
      Cm[(size_t)m * ldc + n] = v;
    }
  }
}

// H = H + sigmoid(*gptr) * (X - H)
__global__ __launch_bounds__(256) void hupdate_kernel(float* __restrict__ H,
    const float* __restrict__ X, const float* __restrict__ gptr){
  size_t i = (size_t)blockIdx.x * 256 + threadIdx.x;
  float g = sigm(*gptr);
  H[i] = H[i] + g * (X[i] - H[i]);
}

extern "C" void kernel_launch(void* const* d_in, const int* in_sizes, int n_in,
                              void* d_out, int out_size, void* d_ws, size_t ws_size,
                              hipStream_t stream){
  const int*   idx        = (const int*)  d_in[0];
  const float* cb         = (const float*)d_in[1];
  const float* decay_lg   = (const float*)d_in[2];
  const float* bv_q       = (const float*)d_in[3];
  const float* bv_k       = (const float*)d_in[4];
  const float* bv_v       = (const float*)d_in[5];
  const float* rules      = (const float*)d_in[6];
  const float* query_bind = (const float*)d_in[7];
  const float* logic_gate = (const float*)d_in[8];
  const float* ln_mem_g   = (const float*)d_in[9];
  const float* ln_mem_b   = (const float*)d_in[10];
  const float* ln_attn_g  = (const float*)d_in[11];
  const float* ln_attn_b  = (const float*)d_in[12];
  const float* ln_logic_g = (const float*)d_in[13];
  const float* ln_logic_b = (const float*)d_in[14];
  const float* ctrl_g     = (const float*)d_in[15];
  const float* ctrl_b     = (const float*)d_in[16];
  const float* down_w     = (const float*)d_in[17];
  const float* down_b     = (const float*)d_in[18];
  const float* up_w       = (const float*)d_in[19];
  const float* up_b       = (const float*)d_in[20];
  const float* tl_gates   = (const float*)d_in[21];
  const float* tl_pos     = (const float*)d_in[22];
  const float* tl_g       = (const float*)d_in[23];
  const float* tl_b       = (const float*)d_in[24];
  const float* out_g      = (const float*)d_in[25];
  const float* out_b      = (const float*)d_in[26];
  const float* oscale     = (const float*)d_in[27];
  float* out = (float*)d_out;

  float* w = (float*)d_ws;
  const size_t ND = (size_t)NTOK * DD;     // 1,048,576
  float* X    = w; w += ND;
  float* H    = w; w += ND;
  float* T0   = w; w += ND;
  float* T1   = w; w += ND;
  float* ATTN = w; w += (size_t)NBAT * TT * TT;   // 131,072
  float* CB   = w; w += (size_t)NTOK * CC;        // 262,144
  float* RW   = w; w += (size_t)NTOK * RR;        // 16,384
  float* SQK  = w; w += (size_t)NBLK * DD;
  float* SV   = w; w += (size_t)NBLK * DD;
  float* SQB  = w; w += (size_t)NBLK * DD;
  float* RLS  = w; w += (size_t)NBLK * RR * DD;   // 262,144

  const float RSD = 0.022097086912079608f;  // D^-0.5

  svec_pair_kernel<<<NBLK, 256, 0, stream>>>(bv_q, bv_k, SQK);
  rowsign_kernel<<<NBLK, 256, 0, stream>>>(bv_v, SV);
  rowsign_kernel<<<NBLK, 256, 0, stream>>>(query_bind, SQB);
  rowsign_kernel<<<NBLK * RR, 256, 0, stream>>>(rules, RLS);
  encode_kernel<<<NTOK, 256, 0, stream>>>(idx, cb, X);

  auto run_blocks = [&](){
    for (int i = 0; i < NBLK; i++){
      const size_t iD = (size_t)i * DD;
      // EMA memory + LN
      ema_kernel<<<dim3(DD/256, NBAT), 256, 0, stream>>>(X, T0, decay_lg + i);
      ln_kernel<<<NTOK, 256, 0, stream>>>(X, T0, ln_mem_g + iD, ln_mem_b + iD,
                                          nullptr, nullptr, X, 1);
      // boolean causal attention
      mm_nt_kernel<1, true><<<dim3(TT/64, TT/64, NBAT), 256, 0, stream>>>(
          X, X, ATTN, TT, TT, DD, DD, DD, TT,
          (long)TT*DD, (long)TT*DD, (long)TT*TT,
          SQK + iD, nullptr, nullptr, nullptr, RSD);
      mm_nn_kernel<<<dim3(DD/64, TT/64, NBAT), 256, 0, stream>>>(
          ATTN, X, T0, TT, DD, TT, TT, DD, DD,
          (long)TT*TT, (long)TT*DD, (long)TT*DD, SV + iD);
      ln_kernel<<<NTOK, 256, 0, stream>>>(X, T0, ln_attn_g + iD, ln_attn_b + iD,
                                          nullptr, nullptr, X, 1);
      // logic layer
      mm_nt_kernel<1, false><<<dim3(1, NTOK/64, 1), 256, 0, stream>>>(
          X, RLS + (size_t)i*RR*DD, RW, NTOK, RR, DD, DD, DD, RR,
          0, 0, 0, SQB + iD, nullptr, nullptr, nullptr, RSD);
      mm_nn_kernel<<<dim3(DD/64, NTOK/64, 1), 256, 0, stream>>>(
          RW, RLS + (size_t)i*RR*DD, T0, NTOK, DD, RR, RR, DD, DD,
          0, 0, 0, nullptr);
      ln_kernel<<<NTOK, 256, 0, stream>>>(X, T0, ln_logic_g + iD, ln_logic_b + iD,
                                          nullptr, logic_gate + i, X, 2);
      // controller MLP
      ln_kernel<<<NTOK, 256, 0, stream>>>(X, nullptr, ctrl_g + iD, ctrl_b + iD,
                                          nullptr, nullptr, T1, 0);
      mm_nt_kernel<2, false><<<dim3(CC/64, NTOK/64, 1), 256, 0, stream>>>(
          T1, down_w + (size_t)i*CC*DD, CB, NTOK, CC, DD, DD, DD, CC,
          0, 0, 0, nullptr, down_b + (size_t)i*CC, nullptr, nullptr, 1.f);
      mm_nt_kernel<0, false><<<dim3(DD/64, NTOK/64, 1), 256, 0, stream>>>(
          CB, up_w + (size_t)i*DD*CC, X, NTOK, DD, CC, CC, CC, DD,
          0, 0, 0, nullptr, up_b + iD, X, nullptr, 1.f);
    }
  };

  run_blocks();
  hipMemcpyAsync(H, X, ND * sizeof(float), hipMemcpyDeviceToDevice, stream);
  for (int ti = 1; ti < MTT; ti++){
    ln_kernel<<<NTOK, 256, 0, stream>>>(H, nullptr, tl_g, tl_b,
                                        tl_pos + (size_t)ti*DD, nullptr, X, 0);
    run_blocks();
    hupdate_kernel<<<ND/256, 256, 0, stream>>>(H, X, tl_gates + ti);
  }
  ln_kernel<<<NTOK, 256, 0, stream>>>(H, nullptr, out_g, out_b, nullptr, nullptr, T1, 0);
  mm_nt_kernel<0, false><<<dim3(VV/64, NTOK/64, 1), 256, 0, stream>>>(
      T1, cb, out, NTOK, VV, DD, DD, DD, VV,
      0, 0, 0, nullptr, nullptr, nullptr, oscale, 1.f);
}

// Round 2
// 2519.772 us; speedup vs baseline: 3.2520x; 3.2520x over previous
//
#include <hip/hip_runtime.h>
#include <math.h>

#define TT   256
#define DD   2048
#define VV   32000
#define NBLK 4
#define CC   512
#define RR   32
#define MTT  3
#define NBAT 2
#define NTOK 512   // NBAT*TT

typedef unsigned int u32;
typedef unsigned short ushort_t;
typedef __attribute__((ext_vector_type(8))) short s16x8;
typedef __attribute__((ext_vector_type(4))) float f32x4;

__device__ __forceinline__ float sigm(float x){ return 1.0f/(1.0f+expf(-x)); }

__device__ __forceinline__ ushort_t f2bf(float f){
  u32 u = __float_as_uint(f);
  u32 r = (u + 0x7fffu + ((u >> 16) & 1u)) >> 16;
  return (ushort_t)r;
}

__device__ __forceinline__ void async_copy16(void* lds, const void* g){
  __builtin_amdgcn_global_load_lds((const __attribute__((address_space(1))) u32*)g,
                                   (__attribute__((address_space(3))) u32*)lds, 16, 0, 0);
}

__device__ __forceinline__ float block_sum256(float v){
  #pragma unroll
  for (int off = 32; off > 0; off >>= 1) v += __shfl_down(v, off);
  __shared__ float sh[4];
  __syncthreads();
  if ((threadIdx.x & 63) == 0) sh[threadIdx.x >> 6] = v;
  __syncthreads();
  return sh[0] + sh[1] + sh[2] + sh[3];
}

// fp32 -> bf16 (RNE), n4 = element_count/4
__global__ __launch_bounds__(256) void cvt_bf16_kernel(const float* __restrict__ in,
    ushort_t* __restrict__ out, long n4){
  long i = (long)blockIdx.x * 256 + threadIdx.x;
  long stride = (long)gridDim.x * 256;
  for (; i < n4; i += stride){
    float4 v = ((const float4*)in)[i];
    ushort4 o;
    o.x = f2bf(v.x); o.y = f2bf(v.y); o.z = f2bf(v.z); o.w = f2bf(v.w);
    ((ushort4*)out)[i] = o;
  }
}

// out[row,d] = alpha_row * sgn0(w[row,d])
__global__ __launch_bounds__(256) void rowsign_kernel(const float* __restrict__ w_,
                                                      float* __restrict__ out){
  size_t row = blockIdx.x;
  const float* w = w_ + row * DD;
  float* o = out + row * DD;
  float s = 0.f;
  #pragma unroll
  for (int j = 0; j < 8; j++) s += fabsf(w[threadIdx.x + j*256]);
  float a = block_sum256(s) * (1.f/DD);
  #pragma unroll
  for (int j = 0; j < 8; j++){
    int d = threadIdx.x + j*256;
    o[d] = (w[d] < 0.f) ? -a : a;
  }
}

// sqk[d] = (mean|q|)(mean|k|) * sgn0(q[d]) * sgn0(k[d])
__global__ __launch_bounds__(256) void svec_pair_kernel(const float* __restrict__ q_,
    const float* __restrict__ k_, float* __restrict__ out_){
  size_t i = blockIdx.x;
  const float* q = q_ + i * DD;
  const float* k = k_ + i * DD;
  float* o = out_ + i * DD;
  float sq = 0.f, sk = 0.f;
  #pragma unroll
  for (int j = 0; j < 8; j++){
    int d = threadIdx.x + j*256;
    sq += fabsf(q[d]); sk += fabsf(k[d]);
  }
  float aq = block_sum256(sq) * (1.f/DD);
  float ak = block_sum256(sk) * (1.f/DD);
  float a2 = aq * ak;
  #pragma unroll
  for (int j = 0; j < 8; j++){
    int d = threadIdx.x + j*256;
    o[d] = ((q[d] < 0.f) != (k[d] < 0.f)) ? -a2 : a2;
  }
}

__global__ __launch_bounds__(256) void encode_kernel(const int* __restrict__ idx,
    const float* __restrict__ cb, float* __restrict__ X){
  int token = blockIdx.x;
  int t = token & (TT - 1);
  size_t row = (size_t)idx[token] * DD;
  float s = 0.f;
  #pragma unroll
  for (int j = 0; j < 8; j++) s += fabsf(cb[row + threadIdx.x + j*256]);
  float a = block_sum256(s) * (1.f/DD);
  #pragma unroll
  for (int j = 0; j < 8; j++){
    int d = threadIdx.x + j*256;
    float w = cb[row + ((d - t) & (DD - 1))];
    X[(size_t)token * DD + d] = (w < 0.f) ? -a : a;
  }
}

// mem[t] = x[t] + decay*mem[t-1]
__global__ __launch_bounds__(256) void ema_kernel(const float* __restrict__ X,
    float* __restrict__ M, const float* __restrict__ dlogit){
  int d = blockIdx.x * 256 + threadIdx.x;
  size_t base = (size_t)blockIdx.y * TT * DD + d;
  float decay = sigm(*dlogit);
  float m = 0.f;
  #pragma unroll 4
  for (int t = 0; t < TT; t++){
    m = fmaf(decay, m, X[base + (size_t)t * DD]);
    M[base + (size_t)t * DD] = m;
  }
}

// mode 0: pre=a; mode 1: pre=a+b; mode 2: pre=a+gate*(b-a)
// y = LN(pre)*g+be (+pos); writes fp32 out, bf16 outb, bf16 outq=y*qscale (each if non-null)
__global__ __launch_bounds__(256) void ln_kernel(const float* __restrict__ A,
    const float* __restrict__ Bb, const float* __restrict__ g, const float* __restrict__ be,
    const float* __restrict__ pos, const float* __restrict__ gate_ptr,
    float* __restrict__ out, ushort_t* __restrict__ outb,
    const float* __restrict__ qscale, ushort_t* __restrict__ outq, int mode){
  size_t row = blockIdx.x;
  const float* a = A + row * DD;
  const float* bb = Bb ? Bb + row * DD : nullptr;
  float gate = (mode == 2) ? sigm(*gate_ptr) : 0.f;
  float vals[8]; float s = 0.f, ss = 0.f;
  #pragma unroll
  for (int j = 0; j < 8; j++){
    int d = threadIdx.x + j*256;
    float v = a[d];
    if (mode == 1) v += bb[d];
    else if (mode == 2) v = v + gate * (bb[d] - v);
    vals[j] = v; s += v; ss += v*v;
  }
  float mean = block_sum256(s) * (1.f/DD);
  float var  = block_sum256(ss) * (1.f/DD) - mean*mean;
  float inv  = rsqrtf(var + 1e-5f);
  #pragma unroll
  for (int j = 0; j < 8; j++){
    int d = threadIdx.x + j*256;
    float y = (vals[j] - mean) * inv * g[d] + be[d];
    if (pos) y += pos[d];
    if (out)  out[row*DD + d] = y;
    if (outb) outb[row*DD + d] = f2bf(y);
    if (outq) outq[row*DD + d] = f2bf(y * qscale[d]);
  }
}

// X[z][T][D] fp32 -> XT[z][D][T] bf16
__global__ __launch_bounds__(256) void transpose_kernel(const float* __restrict__ X,
    ushort_t* __restrict__ XT){
  __shared__ float tile[32][33];
  int z = blockIdx.z;
  int t0 = blockIdx.x << 5, d0 = blockIdx.y << 5;
  int tx = threadIdx.x & 31, ty = threadIdx.x >> 5;
  const float* Xz = X + (size_t)z * TT * DD;
  #pragma unroll
  for (int j = 0; j < 4; j++)
    tile[ty + 8*j][tx] = Xz[(size_t)(t0 + ty + 8*j) * DD + d0 + tx];
  __syncthreads();
  ushort_t* XTz = XT + (size_t)z * DD * TT;
  #pragma unroll
  for (int j = 0; j < 4; j++)
    XTz[(size_t)(d0 + ty + 8*j) * TT + t0 + tx] = f2bf(tile[tx][ty + 8*j]);
}

// fused logic layer: one block per token.
// rw[r] = sigm(4*RSD*sum_d x[d]*SQB[d]*RLS[r][d]); T0[d] = x[d]*sum_r rw[r]*RLS[r][d]
__global__ __launch_bounds__(256) void logic_kernel(const float* __restrict__ X,
    const float* __restrict__ RLSi, const float* __restrict__ SQBi,
    float* __restrict__ T0){
  __shared__ float sh[256*33];
  __shared__ float red[8*32];
  __shared__ float rwsh[32];
  const float RSD = 0.022097086912079608f;
  int tid = threadIdx.x;
  size_t tok = blockIdx.x;
  const float* x = X + tok * DD;
  float xv[8], xq[8];
  #pragma unroll
  for (int j = 0; j < 8; j++){
    int d = tid + 256*j; xv[j] = x[d]; xq[j] = xv[j] * SQBi[d];
  }
  float a[32];
  #pragma unroll 4
  for (int r = 0; r < 32; r++){
    float s = 0.f;
    #pragma unroll
    for (int j = 0; j < 8; j++)
      s = fmaf(xq[j], RLSi[(size_t)r*DD + tid + 256*j], s);
    a[r] = s;
  }
  #pragma unroll
  for (int r = 0; r < 32; r++) sh[tid*33 + r] = a[r];
  __syncthreads();
  {
    int r = tid & 31, g = tid >> 5;
    float s = 0.f;
    #pragma unroll 8
    for (int i = 0; i < 32; i++) s += sh[(g*32 + i)*33 + r];
    red[g*32 + r] = s;
  }
  __syncthreads();
  if (tid < 32){
    float s = 0.f;
    #pragma unroll
    for (int g = 0; g < 8; g++) s += red[g*32 + tid];
    rwsh[tid] = sigm(4.f * RSD * s);
  }
  __syncthreads();
  #pragma unroll
  for (int j = 0; j < 8; j++){
    int d = tid + 256*j;
    float s = 0.f;
    #pragma unroll 8
    for (int r = 0; r < 32; r++)
      s = fmaf(rwsh[r], RLSi[(size_t)r*DD + d], s);
    T0[tok*DD + d] = xv[j] * s;
  }
}

// H = H + sigmoid(*gptr) * (X - H)
__global__ __launch_bounds__(256) void hupdate_kernel(float* __restrict__ H,
    const float* __restrict__ X, const float* __restrict__ gptr){
  size_t i = (size_t)blockIdx.x * 256 + threadIdx.x;
  float g = sigm(*gptr);
  H[i] = H[i] + g * (X[i] - H[i]);
}

// ===================== bf16 MFMA NT GEMM =====================
// C[M,N] = epi( A[M,K] . B[N,K]^T ), A/B bf16 row-major, acc fp32.
// Exact tiling assumed: M%BM==0, N%BN==0, K%64==0.
// Epi: v=acc*alpha(*alpha_ptr); colscale[n]; +bias[n]; ACT(0 none,1 sigm(4v),2 gelu);
//      CAUSAL: n>m -> 0; +res[m,n]; store fp32 or bf16.
template<int BM, int BN, int ACT, bool CAUSAL, bool OUTBF>
__global__ __launch_bounds__(256) void gemm_nt(const ushort_t* __restrict__ A,
    const ushort_t* __restrict__ B, void* __restrict__ Cv,
    int K, int lda, int ldb, int ldc,
    long sA, long sB, long sC,
    const float* __restrict__ colscale, const float* __restrict__ bias,
    const float* __restrict__ res, const float* __restrict__ alpha_ptr, float alpha_c)
{
  constexpr int FM = BM / 32;   // 16-row frags per wave (wave tile BM/2)
  constexpr int FN = BN / 32;
  __shared__ __align__(16) ushort_t shA[BM * 64];
  __shared__ __align__(16) ushort_t shB[BN * 64];
  const int tid = threadIdx.x;
  const int l = tid & 63, w = tid >> 6;
  const int wr = w >> 1, wc = w & 1;
  const int row0 = blockIdx.y * BM, col0 = blockIdx.x * BN;
  A += (size_t)blockIdx.z * sA;
  B += (size_t)blockIdx.z * sB;

  f32x4 acc[FM][FN] = {};

  for (int kt = 0; kt < K; kt += 64){
    // stage A,B tiles: linear LDS dest, inverse-swizzled global source (st-style XOR)
    #pragma unroll
    for (int i = 0; i < BM/32; i++){
      int o = i*4096 + tid*16;
      int r = o >> 7, c = (o >> 4) & 7;
      int lc = c ^ (r & 7);
      async_copy16((char*)shA + o, A + (size_t)(row0 + r) * lda + kt + lc*8);
    }
    #pragma unroll
    for (int i = 0; i < BN/32; i++){
      int o = i*4096 + tid*16;
      int r = o >> 7, c = (o >> 4) & 7;
      int lc = c ^ (r & 7);
      async_copy16((char*)shB + o, B + (size_t)(col0 + r) * ldb + kt + lc*8);
    }
    __syncthreads();
    #pragma unroll
    for (int kk = 0; kk < 2; kk++){
      s16x8 af[FM], bfr[FN];
      #pragma unroll
      for (int mi = 0; mi < FM; mi++){
        int r = wr*(BM/2) + mi*16 + (l & 15);
        int c = kk*4 + (l >> 4);
        af[mi] = *(const s16x8*)((const char*)shA + r*128 + (c ^ (r & 7))*16);
      }
      #pragma unroll
      for (int ni = 0; ni < FN; ni++){
        int r = wc*(BN/2) + ni*16 + (l & 15);
        int c = kk*4 + (l >> 4);
        bfr[ni] = *(const s16x8*)((const char*)shB + r*128 + (c ^ (r & 7))*16);
      }
      #pragma unroll
      for (int mi = 0; mi < FM; mi++)
        #pragma unroll
        for (int ni = 0; ni < FN; ni++)
          acc[mi][ni] = __builtin_amdgcn_mfma_f32_16x16x32_bf16(af[mi], bfr[ni], acc[mi][ni], 0, 0, 0);
    }
    __syncthreads();
  }

  float alpha = alpha_c * (alpha_ptr ? *alpha_ptr : 1.f);
  float* Cf = (float*)Cv + (size_t)blockIdx.z * sC;
  ushort_t* Cb = (ushort_t*)Cv + (size_t)blockIdx.z * sC;
  const float* resz = res ? res + (size_t)blockIdx.z * sC : nullptr;
  #pragma unroll
  for (int mi = 0; mi < FM; mi++){
    #pragma unroll
    for (int ni = 0; ni < FN; ni++){
      #pragma unroll
      for (int j = 0; j < 4; j++){
        int m = row0 + wr*(BM/2) + mi*16 + (l >> 4)*4 + j;
        int n = col0 + wc*(BN/2) + ni*16 + (l & 15);
        float v = acc[mi][ni][j] * alpha;
        if (colscale) v *= colscale[n];
        if (bias) v += bias[n];
        if (ACT == 1) v = sigm(4.f * v);
        else if (ACT == 2) v = 0.5f * v * (1.f + erff(v * 0.70710678118654752f));
        if (CAUSAL && n > m) v = 0.f;
        if (resz) v += resz[(size_t)m * ldc + n];
        if (OUTBF) Cb[(size_t)m * ldc + n] = f2bf(v);
        else       Cf[(size_t)m * ldc + n] = v;
      }
    }
  }
}

extern "C" void kernel_launch(void* const* d_in, const int* in_sizes, int n_in,
                              void* d_out, int out_size, void* d_ws, size_t ws_size,
                              hipStream_t stream){
  const int*   idx        = (const int*)  d_in[0];
  const float* cb         = (const float*)d_in[1];
  const float* decay_lg   = (const float*)d_in[2];
  const float* bv_q       = (const float*)d_in[3];
  const float* bv_k       = (const float*)d_in[4];
  const float* bv_v       = (const float*)d_in[5];
  const float* rules      = (const float*)d_in[6];
  const float* query_bind = (const float*)d_in[7];
  const float* logic_gate = (const float*)d_in[8];
  const float* ln_mem_g   = (const float*)d_in[9];
  const float* ln_mem_b   = (const float*)d_in[10];
  const float* ln_attn_g  = (const float*)d_in[11];
  const float* ln_attn_b  = (const float*)d_in[12];
  const float* ln_logic_g = (const float*)d_in[13];
  const float* ln_logic_b = (const float*)d_in[14];
  const float* ctrl_g     = (const float*)d_in[15];
  const float* ctrl_b     = (const float*)d_in[16];
  const float* down_w     = (const float*)d_in[17];
  const float* down_b     = (const float*)d_in[18];
  const float* up_w       = (const float*)d_in[19];
  const float* up_b       = (const float*)d_in[20];
  const float* tl_gates   = (const float*)d_in[21];
  const float* tl_pos     = (const float*)d_in[22];
  const float* tl_g       = (const float*)d_in[23];
  const float* tl_b       = (const float*)d_in[24];
  const float* out_g      = (const float*)d_in[25];
  const float* out_b      = (const float*)d_in[26];
  const float* oscale     = (const float*)d_in[27];
  float* out = (float*)d_out;

  const size_t ND = (size_t)NTOK * DD;
  char* p = (char*)d_ws;
  auto alloc = [&](size_t bytes){ void* r = p; p += (bytes + 255) & ~(size_t)255; return r; };
  float*    X       = (float*)   alloc(ND * 4);
  float*    H       = (float*)   alloc(ND * 4);
  float*    T0      = (float*)   alloc(ND * 4);
  ushort_t* Xb      = (ushort_t*)alloc(ND * 2);
  ushort_t* Xqb     = (ushort_t*)alloc(ND * 2);
  ushort_t* XbT     = (ushort_t*)alloc(ND * 2);
  ushort_t* T1b     = (ushort_t*)alloc(ND * 2);
  ushort_t* ATTNb   = (ushort_t*)alloc((size_t)NBAT * TT * TT * 2);
  ushort_t* CBb     = (ushort_t*)alloc((size_t)NTOK * CC * 2);
  float*    SQK     = (float*)   alloc((size_t)NBLK * DD * 4);
  float*    SV      = (float*)   alloc((size_t)NBLK * DD * 4);
  float*    SQB     = (float*)   alloc((size_t)NBLK * DD * 4);
  float*    RLS     = (float*)   alloc((size_t)NBLK * RR * DD * 4);
  ushort_t* down_wb = (ushort_t*)alloc((size_t)NBLK * CC * DD * 2);
  ushort_t* up_wb   = (ushort_t*)alloc((size_t)NBLK * DD * CC * 2);
  ushort_t* cb_b    = (ushort_t*)alloc((size_t)VV * DD * 2);

  const float RSD = 0.022097086912079608f;  // D^-0.5

  // ---- one-time prep ----
  svec_pair_kernel<<<NBLK, 256, 0, stream>>>(bv_q, bv_k, SQK);
  rowsign_kernel<<<NBLK, 256, 0, stream>>>(bv_v, SV);
  rowsign_kernel<<<NBLK, 256, 0, stream>>>(query_bind, SQB);
  rowsign_kernel<<<NBLK * RR, 256, 0, stream>>>(rules, RLS);
  cvt_bf16_kernel<<<1024, 256, 0, stream>>>(down_w, down_wb, (long)NBLK*CC*DD/4);
  cvt_bf16_kernel<<<1024, 256, 0, stream>>>(up_w, up_wb, (long)NBLK*DD*CC/4);
  cvt_bf16_kernel<<<2048, 256, 0, stream>>>(cb, cb_b, (long)VV*DD/4);
  encode_kernel<<<NTOK, 256, 0, stream>>>(idx, cb, X);

  auto run_blocks = [&](){
    for (int i = 0; i < NBLK; i++){
      const size_t iD = (size_t)i * DD;
      // EMA memory + LN (emit bf16 X and bf16 X*SQK)
      ema_kernel<<<dim3(DD/256, NBAT), 256, 0, stream>>>(X, T0, decay_lg + i);
      ln_kernel<<<NTOK, 256, 0, stream>>>(X, T0, ln_mem_g + iD, ln_mem_b + iD,
          nullptr, nullptr, X, Xb, SQK + iD, Xqb, 1);
      transpose_kernel<<<dim3(TT/32, DD/32, NBAT), 256, 0, stream>>>(X, XbT);
      // scores = sigm(4*RSD*(Xq . X^T)), causal, bf16 out
      gemm_nt<64,64,1,true,true><<<dim3(TT/64, TT/64, NBAT), 256, 0, stream>>>(
          Xqb, Xb, ATTNb, DD, DD, DD, TT,
          (long)TT*DD, (long)TT*DD, (long)TT*TT,
          nullptr, nullptr, nullptr, nullptr, RSD);
      // att_out = (ATTN . X) * SV[d]
      gemm_nt<64,128,0,false,false><<<dim3(DD/128, TT/64, NBAT), 256, 0, stream>>>(
          ATTNb, XbT, T0, TT, TT, TT, DD,
          (long)TT*TT, (long)DD*TT, (long)TT*DD,
          SV + iD, nullptr, nullptr, nullptr, 1.f);
      ln_kernel<<<NTOK, 256, 0, stream>>>(X, T0, ln_attn_g + iD, ln_attn_b + iD,
          nullptr, nullptr, X, nullptr, nullptr, nullptr, 1);
      // fused logic layer
      logic_kernel<<<NTOK, 256, 0, stream>>>(X, RLS + (size_t)i*RR*DD, SQB + iD, T0);
      ln_kernel<<<NTOK, 256, 0, stream>>>(X, T0, ln_logic_g + iD, ln_logic_b + iD,
          nullptr, logic_gate + i, X, nullptr, nullptr, nullptr, 2);
      // controller MLP
      ln_kernel<<<NTOK, 256, 0, stream>>>(X, nullptr, ctrl_g + iD, ctrl_b + iD,
          nullptr, nullptr, nullptr, T1b, nullptr, nullptr, 0);
      gemm_nt<64,128,2,false,true><<<dim3(CC/128, NTOK/64, 1), 256, 0, stream>>>(
          T1b, down_wb + (size_t)i*CC*DD, CBb, DD, DD, DD, CC,
          0, 0, 0, nullptr, down_b + (size_t)i*CC, nullptr, nullptr, 1.f);
      gemm_nt<64,128,0,false,false><<<dim3(DD/128, NTOK/64, 1), 256, 0, stream>>>(
          CBb, up_wb + (size_t)i*DD*CC, X, CC, CC, CC, DD,
          0, 0, 0, nullptr, up_b + iD, X, nullptr, 1.f);
    }
  };

  run_blocks();
  hipMemcpyAsync(H, X, ND * sizeof(float), hipMemcpyDeviceToDevice, stream);
  for (int ti = 1; ti < MTT; ti++){
    ln_kernel<<<NTOK, 256, 0, stream>>>(H, nullptr, tl_g, tl_b,
        tl_pos + (size_t)ti*DD, nullptr, X, nullptr, nullptr, nullptr, 0);
    run_blocks();
    hupdate_kernel<<<ND/256, 256, 0, stream>>>(H, X, tl_gates + ti);
  }
  ln_kernel<<<NTOK, 256, 0, stream>>>(H, nullptr, out_g, out_b,
      nullptr, nullptr, nullptr, T1b, nullptr, nullptr, 0);
  // logits = (LN(h) . cb^T) * output_scale
  gemm_nt<128,128,0,false,false><<<dim3(VV/128, NTOK/128, 1), 256, 0, stream>>>(
      T1b, cb_b, out, DD, DD, DD, VV,
      0, 0, 0, nullptr, nullptr, nullptr, oscale, 1.f);
}

// Round 3
// 1412.053 us; speedup vs baseline: 5.8031x; 1.7845x over previous
//
#include <hip/hip_runtime.h>
#include <math.h>

#define TT   256
#define DD   2048
#define VV   32000
#define NBLK 4
#define CC   512
#define RR   32
#define MTT  3
#define NBAT 2
#define NTOK 512   // NBAT*TT

typedef unsigned int u32;
typedef unsigned short ushort_t;
typedef __attribute__((ext_vector_type(8))) short s16x8;
typedef __attribute__((ext_vector_type(4))) float f32x4;

__device__ __forceinline__ float sigm(float x){ return 1.0f/(1.0f+expf(-x)); }

__device__ __forceinline__ ushort_t f2bf(float f){
  u32 u = __float_as_uint(f);
  u32 r = (u + 0x7fffu + ((u >> 16) & 1u)) >> 16;
  return (ushort_t)r;
}

__device__ __forceinline__ void async_copy16(void* lds, const void* g){
  __builtin_amdgcn_global_load_lds((const __attribute__((address_space(1))) u32*)g,
                                   (__attribute__((address_space(3))) u32*)lds, 16, 0, 0);
}

__device__ __forceinline__ float block_sum256(float v){
  #pragma unroll
  for (int off = 32; off > 0; off >>= 1) v += __shfl_down(v, off);
  __shared__ float sh[4];
  __syncthreads();
  if ((threadIdx.x & 63) == 0) sh[threadIdx.x >> 6] = v;
  __syncthreads();
  return sh[0] + sh[1] + sh[2] + sh[3];
}

// fp32 -> bf16 (RNE), n4 = element_count/4
__global__ __launch_bounds__(256) void cvt_bf16_kernel(const float* __restrict__ in,
    ushort_t* __restrict__ out, long n4){
  long i = (long)blockIdx.x * 256 + threadIdx.x;
  long stride = (long)gridDim.x * 256;
  for (; i < n4; i += stride){
    float4 v = ((const float4*)in)[i];
    ushort4 o;
    o.x = f2bf(v.x); o.y = f2bf(v.y); o.z = f2bf(v.z); o.w = f2bf(v.w);
    ((ushort4*)out)[i] = o;
  }
}

// out[row,d] = alpha_row * sgn0(w[row,d])
__global__ __launch_bounds__(256) void rowsign_kernel(const float* __restrict__ w_,
                                                      float* __restrict__ out){
  size_t row = blockIdx.x;
  const float* w = w_ + row * DD;
  float* o = out + row * DD;
  float s = 0.f;
  #pragma unroll
  for (int j = 0; j < 8; j++) s += fabsf(w[threadIdx.x + j*256]);
  float a = block_sum256(s) * (1.f/DD);
  #pragma unroll
  for (int j = 0; j < 8; j++){
    int d = threadIdx.x + j*256;
    o[d] = (w[d] < 0.f) ? -a : a;
  }
}

// sqk[d] = (mean|q|)(mean|k|) * sgn0(q[d]) * sgn0(k[d])
__global__ __launch_bounds__(256) void svec_pair_kernel(const float* __restrict__ q_,
    const float* __restrict__ k_, float* __restrict__ out_){
  size_t i = blockIdx.x;
  const float* q = q_ + i * DD;
  const float* k = k_ + i * DD;
  float* o = out_ + i * DD;
  float sq = 0.f, sk = 0.f;
  #pragma unroll
  for (int j = 0; j < 8; j++){
    int d = threadIdx.x + j*256;
    sq += fabsf(q[d]); sk += fabsf(k[d]);
  }
  float aq = block_sum256(sq) * (1.f/DD);
  float ak = block_sum256(sk) * (1.f/DD);
  float a2 = aq * ak;
  #pragma unroll
  for (int j = 0; j < 8; j++){
    int d = threadIdx.x + j*256;
    o[d] = ((q[d] < 0.f) != (k[d] < 0.f)) ? -a2 : a2;
  }
}

__global__ __launch_bounds__(256) void encode_kernel(const int* __restrict__ idx,
    const float* __restrict__ cb, float* __restrict__ X){
  int token = blockIdx.x;
  int t = token & (TT - 1);
  size_t row = (size_t)idx[token] * DD;
  float s = 0.f;
  #pragma unroll
  for (int j = 0; j < 8; j++) s += fabsf(cb[row + threadIdx.x + j*256]);
  float a = block_sum256(s) * (1.f/DD);
  #pragma unroll
  for (int j = 0; j < 8; j++){
    int d = threadIdx.x + j*256;
    float w = cb[row + ((d - t) & (DD - 1))];
    X[(size_t)token * DD + d] = (w < 0.f) ? -a : a;
  }
}

// Adec[i][t][s] = decay_i^(t-s) (t>=s) else 0, bf16.  grid (TT, NBLK)
__global__ __launch_bounds__(256) void adec_kernel(const float* __restrict__ decay_logit,
    ushort_t* __restrict__ Adec){
  int i = blockIdx.y, t = blockIdx.x, s = threadIdx.x;
  float decay = sigm(decay_logit[i]);
  float l2 = log2f(decay);
  int e = t - s;
  float v = (e < 0) ? 0.f : exp2f((float)e * l2);
  Adec[((size_t)i*TT + t)*TT + s] = f2bf(v);
}

// LN: pre = A[row]; y=LN(pre)*g+be; writes fp32 out, bf16 outb, bf16 outq=y*qscale
__global__ __launch_bounds__(256) void ln_kernel(const float* __restrict__ A,
    const float* __restrict__ g, const float* __restrict__ be,
    float* __restrict__ out, ushort_t* __restrict__ outb,
    const float* __restrict__ qscale, ushort_t* __restrict__ outq){
  size_t row = blockIdx.x;
  const float* a = A + row * DD;
  float vals[8]; float s = 0.f, ss = 0.f;
  #pragma unroll
  for (int j = 0; j < 8; j++){
    int d = threadIdx.x + j*256;
    float v = a[d];
    vals[j] = v; s += v; ss += v*v;
  }
  float mean = block_sum256(s) * (1.f/DD);
  float var  = block_sum256(ss) * (1.f/DD) - mean*mean;
  float inv  = rsqrtf(var + 1e-5f);
  #pragma unroll
  for (int j = 0; j < 8; j++){
    int d = threadIdx.x + j*256;
    float y = (vals[j] - mean) * inv * g[d] + be[d];
    if (out)  out[row*DD + d] = y;
    if (outb) outb[row*DD + d] = f2bf(y);
    if (outq) outq[row*DD + d] = f2bf(y * qscale[d]);
  }
}

// X[z][T][D] fp32 -> XT[z][D][T] bf16
__global__ __launch_bounds__(256) void transpose_kernel(const float* __restrict__ X,
    ushort_t* __restrict__ XT){
  __shared__ float tile[32][33];
  int z = blockIdx.z;
  int t0 = blockIdx.x << 5, d0 = blockIdx.y << 5;
  int tx = threadIdx.x & 31, ty = threadIdx.x >> 5;
  const float* Xz = X + (size_t)z * TT * DD;
  #pragma unroll
  for (int j = 0; j < 4; j++)
    tile[ty + 8*j][tx] = Xz[(size_t)(t0 + ty + 8*j) * DD + d0 + tx];
  __syncthreads();
  ushort_t* XTz = XT + (size_t)z * DD * TT;
  #pragma unroll
  for (int j = 0; j < 4; j++)
    XTz[(size_t)(d0 + ty + 8*j) * TT + t0 + tx] = f2bf(tile[tx][ty + 8*j]);
}

// Mega-fused: y2=LN(T0)*g2+b2 (attn LN); logic layer on y2; pre3=y2+gate*(lo-y2);
// y3=LN(pre3)*g3+b3 -> X; y4=LN(y3)*g4+b4 -> T1b (bf16).  One block per token.
__global__ __launch_bounds__(256) void fuse_logic_kernel(const float* __restrict__ T0,
    const float* __restrict__ RLSi, const float* __restrict__ SQBi,
    const float* __restrict__ g2, const float* __restrict__ b2,
    const float* __restrict__ gate_ptr,
    const float* __restrict__ g3, const float* __restrict__ b3,
    const float* __restrict__ g4, const float* __restrict__ b4,
    float* __restrict__ X, ushort_t* __restrict__ T1b){
  __shared__ float sh[256*33];
  __shared__ float red[8*32];
  __shared__ float rwsh[32];
  const float RSD = 0.022097086912079608f;
  int tid = threadIdx.x;
  size_t tok = blockIdx.x;
  const float* a = T0 + tok * DD;
  float v[8]; float s = 0.f, ss = 0.f;
  #pragma unroll
  for (int j = 0; j < 8; j++){
    int d = tid + 256*j;
    v[j] = a[d]; s += v[j]; ss += v[j]*v[j];
  }
  float mean = block_sum256(s) * (1.f/DD);
  float var  = block_sum256(ss) * (1.f/DD) - mean*mean;
  float inv  = rsqrtf(var + 1e-5f);
  float y2[8], xq[8];
  #pragma unroll
  for (int j = 0; j < 8; j++){
    int d = tid + 256*j;
    y2[j] = (v[j] - mean) * inv * g2[d] + b2[d];
    xq[j] = y2[j] * SQBi[d];
  }
  // rule sims
  float aa[32];
  #pragma unroll 4
  for (int r = 0; r < 32; r++){
    float t = 0.f;
    #pragma unroll
    for (int j = 0; j < 8; j++)
      t = fmaf(xq[j], RLSi[(size_t)r*DD + tid + 256*j], t);
    aa[r] = t;
  }
  #pragma unroll
  for (int r = 0; r < 32; r++) sh[tid*33 + r] = aa[r];
  __syncthreads();
  {
    int r = tid & 31, gg = tid >> 5;
    float t = 0.f;
    #pragma unroll 8
    for (int i = 0; i < 32; i++) t += sh[(gg*32 + i)*33 + r];
    red[gg*32 + r] = t;
  }
  __syncthreads();
  if (tid < 32){
    float t = 0.f;
    #pragma unroll
    for (int gg = 0; gg < 8; gg++) t += red[gg*32 + tid];
    rwsh[tid] = sigm(4.f * RSD * t);
  }
  __syncthreads();
  float gate = sigm(*gate_ptr);
  float p3[8]; s = 0.f; ss = 0.f;
  #pragma unroll
  for (int j = 0; j < 8; j++){
    int d = tid + 256*j;
    float t = 0.f;
    #pragma unroll 8
    for (int r = 0; r < 32; r++)
      t = fmaf(rwsh[r], RLSi[(size_t)r*DD + d], t);
    float lo = y2[j] * t;
    p3[j] = y2[j] + gate * (lo - y2[j]);
    s += p3[j]; ss += p3[j]*p3[j];
  }
  mean = block_sum256(s) * (1.f/DD);
  var  = block_sum256(ss) * (1.f/DD) - mean*mean;
  inv  = rsqrtf(var + 1e-5f);
  float y3[8]; s = 0.f; ss = 0.f;
  #pragma unroll
  for (int j = 0; j < 8; j++){
    int d = tid + 256*j;
    y3[j] = (p3[j] - mean) * inv * g3[d] + b3[d];
    X[tok*DD + d] = y3[j];
    s += y3[j]; ss += y3[j]*y3[j];
  }
  mean = block_sum256(s) * (1.f/DD);
  var  = block_sum256(ss) * (1.f/DD) - mean*mean;
  inv  = rsqrtf(var + 1e-5f);
  #pragma unroll
  for (int j = 0; j < 8; j++){
    int d = tid + 256*j;
    T1b[tok*DD + d] = f2bf((y3[j] - mean) * inv * g4[d] + b4[d]);
  }
}

// Thought-loop glue: Hnew = (gate? H + sigm(*gate)*(Xr-H) : Xr); H=Hnew (if writeH);
// y = LN(Hnew)*g+b (+pos); -> fp32 outX or bf16 outb.
__global__ __launch_bounds__(256) void tl_kernel(const float* __restrict__ Xr,
    float* __restrict__ H, const float* __restrict__ gate_ptr,
    const float* __restrict__ g, const float* __restrict__ be,
    const float* __restrict__ pos,
    float* __restrict__ outX, ushort_t* __restrict__ outb){
  size_t row = blockIdx.x;
  float gate = gate_ptr ? sigm(*gate_ptr) : 1.f;
  float v[8]; float s = 0.f, ss = 0.f;
  #pragma unroll
  for (int j = 0; j < 8; j++){
    int d = threadIdx.x + j*256;
    float xr = Xr[row*DD + d];
    float hv = gate_ptr ? H[row*DD + d] : 0.f;
    float hn = gate_ptr ? (hv + gate * (xr - hv)) : xr;
    H[row*DD + d] = hn;
    v[j] = hn; s += hn; ss += hn*hn;
  }
  float mean = block_sum256(s) * (1.f/DD);
  float var  = block_sum256(ss) * (1.f/DD) - mean*mean;
  float inv  = rsqrtf(var + 1e-5f);
  #pragma unroll
  for (int j = 0; j < 8; j++){
    int d = threadIdx.x + j*256;
    float y = (v[j] - mean) * inv * g[d] + be[d];
    if (pos) y += pos[d];
    if (outX) outX[row*DD + d] = y;
    if (outb) outb[row*DD + d] = f2bf(y);
  }
}

// ===================== bf16 MFMA NT GEMM (+split-K) =====================
// C = epi(A[M,K] . B[N,K]^T). SPLITK>1: z=(zb*SPLITK+zk); k in [zk*K/S,(zk+1)*K/S);
// raw fp32 partial stored at Cv + z*sC (no epilogue). SPLITK==1: full epilogue.
template<int BM, int BN, int SPLITK, int ACT, bool CAUSAL, bool OUTBF>
__global__ __launch_bounds__(256) void gemm_nt(const ushort_t* __restrict__ A,
    const ushort_t* __restrict__ B, void* __restrict__ Cv,
    int K, int lda, int ldb, int ldc,
    long sA, long sB, long sC,
    const float* __restrict__ colscale, const float* __restrict__ bias,
    const float* __restrict__ res, const float* __restrict__ alpha_ptr, float alpha_c)
{
  constexpr int FM = BM / 32;
  constexpr int FN = BN / 32;
  __shared__ __align__(16) ushort_t shA[BM * 64];
  __shared__ __align__(16) ushort_t shB[BN * 64];
  const int tid = threadIdx.x;
  const int l = tid & 63, w = tid >> 6;
  const int wr = w >> 1, wc = w & 1;
  const int row0 = blockIdx.y * BM, col0 = blockIdx.x * BN;
  const int zb = blockIdx.z / SPLITK, zk = blockIdx.z % SPLITK;

  if (CAUSAL && col0 > row0 + BM - 1){
    if (SPLITK > 1) return;             // reduce kernel masks these
    // write zeros (unused path kept correct)
    for (int i = tid; i < BM*BN; i += 256){
      int m = row0 + i / BN, n = col0 + i % BN;
      if (OUTBF) ((ushort_t*)Cv)[(size_t)zb*sC + (size_t)m*ldc + n] = f2bf(0.f);
      else       ((float*)Cv)[(size_t)zb*sC + (size_t)m*ldc + n] = 0.f;
    }
    return;
  }

  A += (size_t)zb * sA;
  B += (size_t)zb * sB;
  const int kbeg = zk * (K / SPLITK), kend = kbeg + K / SPLITK;

  f32x4 acc[FM][FN] = {};

  for (int kt = kbeg; kt < kend; kt += 64){
    #pragma unroll
    for (int i = 0; i < BM/32; i++){
      int o = i*4096 + tid*16;
      int r = o >> 7, c = (o >> 4) & 7;
      int lc = c ^ (r & 7);
      async_copy16((char*)shA + o, A + (size_t)(row0 + r) * lda + kt + lc*8);
    }
    #pragma unroll
    for (int i = 0; i < BN/32; i++){
      int o = i*4096 + tid*16;
      int r = o >> 7, c = (o >> 4) & 7;
      int lc = c ^ (r & 7);
      async_copy16((char*)shB + o, B + (size_t)(col0 + r) * ldb + kt + lc*8);
    }
    __syncthreads();
    #pragma unroll
    for (int kk = 0; kk < 2; kk++){
      s16x8 af[FM], bfr[FN];
      #pragma unroll
      for (int mi = 0; mi < FM; mi++){
        int r = wr*(BM/2) + mi*16 + (l & 15);
        int c = kk*4 + (l >> 4);
        af[mi] = *(const s16x8*)((const char*)shA + r*128 + (c ^ (r & 7))*16);
      }
      #pragma unroll
      for (int ni = 0; ni < FN; ni++){
        int r = wc*(BN/2) + ni*16 + (l & 15);
        int c = kk*4 + (l >> 4);
        bfr[ni] = *(const s16x8*)((const char*)shB + r*128 + (c ^ (r & 7))*16);
      }
      #pragma unroll
      for (int mi = 0; mi < FM; mi++)
        #pragma unroll
        for (int ni = 0; ni < FN; ni++)
          acc[mi][ni] = __builtin_amdgcn_mfma_f32_16x16x32_bf16(af[mi], bfr[ni], acc[mi][ni], 0, 0, 0);
    }
    __syncthreads();
  }

  if (SPLITK > 1){
    float* P = (float*)Cv + (size_t)blockIdx.z * sC;
    #pragma unroll
    for (int mi = 0; mi < FM; mi++)
      #pragma unroll
      for (int ni = 0; ni < FN; ni++)
        #pragma unroll
        for (int j = 0; j < 4; j++){
          int m = row0 + wr*(BM/2) + mi*16 + (l >> 4)*4 + j;
          int n = col0 + wc*(BN/2) + ni*16 + (l & 15);
          P[(size_t)m * ldc + n] = acc[mi][ni][j];
        }
    return;
  }

  float alpha = alpha_c * (alpha_ptr ? *alpha_ptr : 1.f);
  float* Cf = (float*)Cv + (size_t)zb * sC;
  ushort_t* Cb = (ushort_t*)Cv + (size_t)zb * sC;
  const float* resz = res ? res + (size_t)zb * sC : nullptr;
  #pragma unroll
  for (int mi = 0; mi < FM; mi++){
    #pragma unroll
    for (int ni = 0; ni < FN; ni++){
      #pragma unroll
      for (int j = 0; j < 4; j++){
        int m = row0 + wr*(BM/2) + mi*16 + (l >> 4)*4 + j;
        int n = col0 + wc*(BN/2) + ni*16 + (l & 15);
        float v = acc[mi][ni][j] * alpha;
        if (colscale) v *= colscale[n];
        if (bias) v += bias[n];
        if (ACT == 1) v = sigm(4.f * v);
        else if (ACT == 2) v = 0.5f * v * (1.f + erff(v * 0.70710678118654752f));
        if (CAUSAL && n > m) v = 0.f;
        if (resz) v += resz[(size_t)m * ldc + n];
        if (OUTBF) Cb[(size_t)m * ldc + n] = f2bf(v);
        else       Cf[(size_t)m * ldc + n] = v;
      }
    }
  }
}

// split-K reduce + epilogue. P: [nb*S][M*N] fp32. out: [nb][M*N].
// v = alpha*sum_s P + bias[n]; ACT; CAUSAL(n>m -> 0); OUTBF.
template<int S, int ACT, bool CAUSAL, bool OUTBF>
__global__ __launch_bounds__(256) void reduce_epi(const float* __restrict__ P,
    void* __restrict__ outv, int M, int N, const float* __restrict__ bias, float alpha){
  long MN = (long)M * N;
  long idx = ((long)blockIdx.x * 256 + threadIdx.x) * 4;
  int b = (int)(idx / MN);
  long r = idx - (long)b * MN;
  int m = (int)(r / N), n = (int)(r % N);
  float vv[4] = {0.f, 0.f, 0.f, 0.f};
  #pragma unroll
  for (int s = 0; s < S; s++){
    float4 p = *(const float4*)&P[((long)(b*S + s)) * MN + r];
    vv[0] += p.x; vv[1] += p.y; vv[2] += p.z; vv[3] += p.w;
  }
  ushort4 ob; float4 of;
  float* po = (float*)&of;
  ushort_t* pb = (ushort_t*)&ob;
  #pragma unroll
  for (int j = 0; j < 4; j++){
    float v = vv[j] * alpha;
    if (bias) v += bias[n + j];
    if (ACT == 1) v = sigm(4.f * v);
    else if (ACT == 2) v = 0.5f * v * (1.f + erff(v * 0.70710678118654752f));
    if (CAUSAL && n + j > m) v = 0.f;
    po[j] = v; pb[j] = f2bf(v);
  }
  if (OUTBF) *(ushort4*)&((ushort_t*)outv)[(long)b*MN + r] = ob;
  else       *(float4*)&((float*)outv)[(long)b*MN + r] = of;
}

extern "C" void kernel_launch(void* const* d_in, const int* in_sizes, int n_in,
                              void* d_out, int out_size, void* d_ws, size_t ws_size,
                              hipStream_t stream){
  const int*   idx        = (const int*)  d_in[0];
  const float* cb         = (const float*)d_in[1];
  const float* decay_lg   = (const float*)d_in[2];
  const float* bv_q       = (const float*)d_in[3];
  const float* bv_k       = (const float*)d_in[4];
  const float* bv_v       = (const float*)d_in[5];
  const float* rules      = (const float*)d_in[6];
  const float* query_bind = (const float*)d_in[7];
  const float* logic_gate = (const float*)d_in[8];
  const float* ln_mem_g   = (const float*)d_in[9];
  const float* ln_mem_b   = (const float*)d_in[10];
  const float* ln_attn_g  = (const float*)d_in[11];
  const float* ln_attn_b  = (const float*)d_in[12];
  const float* ln_logic_g = (const float*)d_in[13];
  const float* ln_logic_b = (const float*)d_in[14];
  const float* ctrl_g     = (const float*)d_in[15];
  const float* ctrl_b     = (const float*)d_in[16];
  const float* down_w     = (const float*)d_in[17];
  const float* down_b     = (const float*)d_in[18];
  const float* up_w       = (const float*)d_in[19];
  const float* up_b       = (const float*)d_in[20];
  const float* tl_gates   = (const float*)d_in[21];
  const float* tl_pos     = (const float*)d_in[22];
  const float* tl_g       = (const float*)d_in[23];
  const float* tl_b       = (const float*)d_in[24];
  const float* out_g      = (const float*)d_in[25];
  const float* out_b      = (const float*)d_in[26];
  const float* oscale     = (const float*)d_in[27];
  float* out = (float*)d_out;

  const size_t ND = (size_t)NTOK * DD;
  char* p = (char*)d_ws;
  auto alloc = [&](size_t bytes){ void* r = p; p += (bytes + 255) & ~(size_t)255; return r; };
  float*    X       = (float*)   alloc(ND * 4);
  float*    H       = (float*)   alloc(ND * 4);
  float*    T0      = (float*)   alloc(ND * 4);   // also aliased by PS / PD between uses
  ushort_t* XT      = (ushort_t*)alloc(ND * 2);
  ushort_t* Xb      = (ushort_t*)alloc(ND * 2);
  ushort_t* Xqb     = (ushort_t*)alloc(ND * 2);
  ushort_t* T1b     = (ushort_t*)alloc(ND * 2);
  ushort_t* ATTNb   = (ushort_t*)alloc((size_t)NBAT * TT * TT * 2);
  ushort_t* CBb     = (ushort_t*)alloc((size_t)NTOK * CC * 2);
  float*    SQK     = (float*)   alloc((size_t)NBLK * DD * 4);
  float*    SV      = (float*)   alloc((size_t)NBLK * DD * 4);
  float*    SQB     = (float*)   alloc((size_t)NBLK * DD * 4);
  float*    RLS     = (float*)   alloc((size_t)NBLK * RR * DD * 4);
  ushort_t* Adec    = (ushort_t*)alloc((size_t)NBLK * TT * TT * 2);
  ushort_t* down_wb = (ushort_t*)alloc((size_t)NBLK * CC * DD * 2);
  ushort_t* up_wb   = (ushort_t*)alloc((size_t)NBLK * DD * CC * 2);
  ushort_t* cb_b    = (ushort_t*)alloc((size_t)VV * DD * 2);
  float* PS = T0;   // scores partials [NBAT*4][TT*TT] fp32 = 2MB, alias T0 (free then)
  float* PD = T0;   // down partials  [4][NTOK*CC] fp32 = 4MB, alias T0 (free then)

  const float RSD = 0.022097086912079608f;  // D^-0.5

  // ---- one-time prep ----
  svec_pair_kernel<<<NBLK, 256, 0, stream>>>(bv_q, bv_k, SQK);
  rowsign_kernel<<<NBLK, 256, 0, stream>>>(bv_v, SV);
  rowsign_kernel<<<NBLK, 256, 0, stream>>>(query_bind, SQB);
  rowsign_kernel<<<NBLK * RR, 256, 0, stream>>>(rules, RLS);
  adec_kernel<<<dim3(TT, NBLK), 256, 0, stream>>>(decay_lg, Adec);
  cvt_bf16_kernel<<<1024, 256, 0, stream>>>(down_w, down_wb, (long)NBLK*CC*DD/4);
  cvt_bf16_kernel<<<1024, 256, 0, stream>>>(up_w, up_wb, (long)NBLK*DD*CC/4);
  cvt_bf16_kernel<<<4096, 256, 0, stream>>>(cb, cb_b, (long)VV*DD/4);
  encode_kernel<<<NTOK, 256, 0, stream>>>(idx, cb, X);

  auto run_blocks = [&](){
    for (int i = 0; i < NBLK; i++){
      const size_t iD = (size_t)i * DD;
      // --- EMA as matmul: T0 = Adec_i @ X + X ---
      transpose_kernel<<<dim3(TT/32, DD/32, NBAT), 256, 0, stream>>>(X, XT);
      gemm_nt<64,64,1,0,false,false><<<dim3(DD/64, TT/64, NBAT), 256, 0, stream>>>(
          Adec + (size_t)i*TT*TT, XT, T0, TT, TT, TT, DD,
          0, (long)DD*TT, (long)TT*DD,
          nullptr, nullptr, X, nullptr, 1.f);
      // --- LN_mem -> X (fp32), Xb, Xqb=X*SQK ---
      ln_kernel<<<NTOK, 256, 0, stream>>>(T0, ln_mem_g + iD, ln_mem_b + iD,
          X, Xb, SQK + iD, Xqb);
      // --- scores (split-K 4) + reduce(sigmoid4, causal) -> ATTNb ---
      gemm_nt<64,64,4,0,true,false><<<dim3(TT/64, TT/64, NBAT*4), 256, 0, stream>>>(
          Xqb, Xb, PS, DD, DD, DD, TT,
          (long)TT*DD, (long)TT*DD, (long)TT*TT,
          nullptr, nullptr, nullptr, nullptr, 1.f);
      reduce_epi<4,1,true,true><<<(NBAT*TT*TT)/1024, 256, 0, stream>>>(
          PS, ATTNb, TT, TT, nullptr, RSD);
      // --- att_out: T0 = (ATTN @ X1)*SV + X1 ---
      transpose_kernel<<<dim3(TT/32, DD/32, NBAT), 256, 0, stream>>>(X, XT);
      gemm_nt<64,64,1,0,false,false><<<dim3(DD/64, TT/64, NBAT), 256, 0, stream>>>(
          ATTNb, XT, T0, TT, TT, TT, DD,
          (long)TT*TT, (long)DD*TT, (long)TT*DD,
          SV + iD, nullptr, X, nullptr, 1.f);
      // --- mega-fused LN_attn + logic + gate + LN_logic + ctrl-LN ---
      fuse_logic_kernel<<<NTOK, 256, 0, stream>>>(T0,
          RLS + (size_t)i*RR*DD, SQB + iD,
          ln_attn_g + iD, ln_attn_b + iD, logic_gate + i,
          ln_logic_g + iD, ln_logic_b + iD, ctrl_g + iD, ctrl_b + iD,
          X, T1b);
      // --- MLP down (split-K 4) + reduce(bias, gelu) -> CBb ---
      gemm_nt<64,64,4,0,false,false><<<dim3(CC/64, NTOK/64, 4), 256, 0, stream>>>(
          T1b, down_wb + (size_t)i*CC*DD, PD, DD, DD, DD, CC,
          0, 0, (long)NTOK*CC,
          nullptr, nullptr, nullptr, nullptr, 1.f);
      reduce_epi<4,2,false,true><<<(NTOK*CC)/1024, 256, 0, stream>>>(
          PD, CBb, NTOK, CC, down_b + (size_t)i*CC, 1.f);
      // --- MLP up: X = CBb @ up_w^T + bias + X ---
      gemm_nt<64,64,1,0,false,false><<<dim3(DD/64, NTOK/64, 1), 256, 0, stream>>>(
          CBb, up_wb + (size_t)i*DD*CC, X, CC, CC, CC, DD,
          0, 0, 0, nullptr, up_b + iD, X, nullptr, 1.f);
    }
  };

  run_blocks();
  // ti=1: H = X; X = LN(H)*tl_g+tl_b + pos[1]
  tl_kernel<<<NTOK, 256, 0, stream>>>(X, H, nullptr, tl_g, tl_b,
      tl_pos + (size_t)1*DD, X, nullptr);
  run_blocks();
  // ti=2: H += s(g1)(X-H); X = LN(H) + pos[2]
  tl_kernel<<<NTOK, 256, 0, stream>>>(X, H, tl_gates + 1, tl_g, tl_b,
      tl_pos + (size_t)2*DD, X, nullptr);
  run_blocks();
  // final: H += s(g2)(X-H); T1b = bf16(LN(H)*out_g+out_b)
  tl_kernel<<<NTOK, 256, 0, stream>>>(X, H, tl_gates + 2, out_g, out_b,
      nullptr, nullptr, T1b);
  // logits = (LN(h) . cb^T) * output_scale
  gemm_nt<128,128,1,0,false,false><<<dim3(VV/128, NTOK/128, 1), 256, 0, stream>>>(
      T1b, cb_b, out, DD, DD, DD, VV,
      0, 0, 0, nullptr, nullptr, nullptr, oscale, 1.f);
}

// Round 5
// 1247.692 us; speedup vs baseline: 6.5676x; 1.1317x over previous
//
#include <hip/hip_runtime.h>
#include <math.h>

#define TT   256
#define DD   2048
#define VV   32000
#define NBLK 4
#define CC   512
#define RR   32
#define MTT  3
#define NBAT 2
#define NTOK 512   // NBAT*TT

typedef unsigned int u32;
typedef unsigned short ushort_t;
typedef __attribute__((ext_vector_type(8))) short s16x8;
typedef __attribute__((ext_vector_type(4))) float f32x4;

__device__ __forceinline__ float sigm(float x){ return 1.0f/(1.0f+expf(-x)); }

__device__ __forceinline__ ushort_t f2bf(float f){
  u32 u = __float_as_uint(f);
  u32 r = (u + 0x7fffu + ((u >> 16) & 1u)) >> 16;
  return (ushort_t)r;
}
__device__ __forceinline__ float bf2f(ushort_t u){
  return __uint_as_float(((u32)u) << 16);
}

__device__ __forceinline__ void async_copy16(void* lds, const void* g){
  __builtin_amdgcn_global_load_lds((const __attribute__((address_space(1))) u32*)g,
                                   (__attribute__((address_space(3))) u32*)lds, 16, 0, 0);
}

__device__ __forceinline__ float block_sum256(float v){
  #pragma unroll
  for (int off = 32; off > 0; off >>= 1) v += __shfl_down(v, off);
  __shared__ float sh[4];
  __syncthreads();
  if ((threadIdx.x & 63) == 0) sh[threadIdx.x >> 6] = v;
  __syncthreads();
  return sh[0] + sh[1] + sh[2] + sh[3];
}

// fp32 -> bf16 for two tensors in one launch
__global__ __launch_bounds__(256) void cvt2_kernel(const float* __restrict__ a,
    ushort_t* __restrict__ oa, long na4,
    const float* __restrict__ b, ushort_t* __restrict__ ob, long nb4){
  long i = (long)blockIdx.x * 256 + threadIdx.x;
  long stride = (long)gridDim.x * 256;
  long tot = na4 + nb4;
  for (; i < tot; i += stride){
    const float* src = (i < na4) ? a : b;
    ushort_t* dst = (i < na4) ? oa : ob;
    long k = (i < na4) ? i : i - na4;
    float4 v = ((const float4*)src)[k];
    ushort4 o;
    o.x = f2bf(v.x); o.y = f2bf(v.y); o.z = f2bf(v.z); o.w = f2bf(v.w);
    ((ushort4*)dst)[k] = o;
  }
}

// one kernel for all sign-vector prep:
// blocks [0,NB): SQK; [NB,2NB): SV; [2NB,3NB): SQB; [3NB,3NB+NB*RR): RLSb (bf16)
__global__ __launch_bounds__(256) void sign_prep_kernel(
    const float* __restrict__ bv_q, const float* __restrict__ bv_k,
    const float* __restrict__ bv_v, const float* __restrict__ query_bind,
    const float* __restrict__ rules,
    float* __restrict__ SQK, float* __restrict__ SV, float* __restrict__ SQB,
    ushort_t* __restrict__ RLSb){
  int b = blockIdx.x;
  if (b < NBLK){
    const float* q = bv_q + (size_t)b * DD;
    const float* k = bv_k + (size_t)b * DD;
    float sq = 0.f, sk = 0.f;
    #pragma unroll
    for (int j = 0; j < 8; j++){
      int d = threadIdx.x + j*256;
      sq += fabsf(q[d]); sk += fabsf(k[d]);
    }
    float aq = block_sum256(sq) * (1.f/DD);
    float ak = block_sum256(sk) * (1.f/DD);
    float a2 = aq * ak;
    float* o = SQK + (size_t)b * DD;
    #pragma unroll
    for (int j = 0; j < 8; j++){
      int d = threadIdx.x + j*256;
      o[d] = ((q[d] < 0.f) != (k[d] < 0.f)) ? -a2 : a2;
    }
    return;
  }
  const float* w; float* of = nullptr; ushort_t* ob = nullptr;
  if (b < 2*NBLK){ w = bv_v + (size_t)(b - NBLK) * DD; of = SV + (size_t)(b - NBLK) * DD; }
  else if (b < 3*NBLK){ w = query_bind + (size_t)(b - 2*NBLK) * DD; of = SQB + (size_t)(b - 2*NBLK) * DD; }
  else { int r = b - 3*NBLK; w = rules + (size_t)r * DD; ob = RLSb + (size_t)r * DD; }
  float s = 0.f;
  #pragma unroll
  for (int j = 0; j < 8; j++) s += fabsf(w[threadIdx.x + j*256]);
  float a = block_sum256(s) * (1.f/DD);
  #pragma unroll
  for (int j = 0; j < 8; j++){
    int d = threadIdx.x + j*256;
    float v = (w[d] < 0.f) ? -a : a;
    if (of) of[d] = v;
    else    ob[d] = f2bf(v);
  }
}

__global__ __launch_bounds__(256) void encode_kernel(const int* __restrict__ idx,
    const float* __restrict__ cb, float* __restrict__ X, ushort_t* __restrict__ Xrb){
  int token = blockIdx.x;
  int t = token & (TT - 1);
  size_t row = (size_t)idx[token] * DD;
  float s = 0.f;
  #pragma unroll
  for (int j = 0; j < 8; j++) s += fabsf(cb[row + threadIdx.x + j*256]);
  float a = block_sum256(s) * (1.f/DD);
  #pragma unroll
  for (int j = 0; j < 8; j++){
    int d = threadIdx.x + j*256;
    float w = cb[row + ((d - t) & (DD - 1))];
    float v = (w < 0.f) ? -a : a;
    X[(size_t)token * DD + d] = v;
    Xrb[(size_t)token * DD + d] = f2bf(v);
  }
}

// Adec[i][t][s] = decay_i^(t-s) (t>=s) else 0, bf16.  grid (TT, NBLK)
__global__ __launch_bounds__(256) void adec_kernel(const float* __restrict__ decay_logit,
    ushort_t* __restrict__ Adec){
  int i = blockIdx.y, t = blockIdx.x, s = threadIdx.x;
  float decay = sigm(decay_logit[i]);
  float l2 = log2f(decay);
  int e = t - s;
  float v = (e < 0) ? 0.f : exp2f((float)e * l2);
  Adec[((size_t)i*TT + t)*TT + s] = f2bf(v);
}

// y=LN(A[row])*g+be; writes fp32 out, bf16 outb, bf16 outq=y*qscale, bf16 outv=y*vscale
__global__ __launch_bounds__(256) void ln_kernel(const float* __restrict__ A,
    const float* __restrict__ g, const float* __restrict__ be,
    float* __restrict__ out, ushort_t* __restrict__ outb,
    const float* __restrict__ qscale, ushort_t* __restrict__ outq,
    const float* __restrict__ vscale, ushort_t* __restrict__ outv){
  size_t row = blockIdx.x;
  const float* a = A + row * DD;
  float vals[8]; float s = 0.f, ss = 0.f;
  #pragma unroll
  for (int j = 0; j < 8; j++){
    int d = threadIdx.x + j*256;
    float v = a[d];
    vals[j] = v; s += v; ss += v*v;
  }
  float mean = block_sum256(s) * (1.f/DD);
  float var  = block_sum256(ss) * (1.f/DD) - mean*mean;
  float inv  = rsqrtf(var + 1e-5f);
  #pragma unroll
  for (int j = 0; j < 8; j++){
    int d = threadIdx.x + j*256;
    float y = (vals[j] - mean) * inv * g[d] + be[d];
    if (out)  out[row*DD + d] = y;
    if (outb) outb[row*DD + d] = f2bf(y);
    if (outq) outq[row*DD + d] = f2bf(y * qscale[d]);
    if (outv) outv[row*DD + d] = f2bf(y * vscale[d]);
  }
}

// Mega-fused: y2=LN(T0)*g2+b2; logic on y2; pre3=y2+gate*(lo-y2);
// y3=LN(pre3)*g3+b3 -> X; y4=LN(y3)*g4+b4 -> T1b (bf16).  One block per token.
__global__ __launch_bounds__(256) void fuse_logic_kernel(const float* __restrict__ T0,
    const ushort_t* __restrict__ RLSi, const float* __restrict__ SQBi,
    const float* __restrict__ g2, const float* __restrict__ b2,
    const float* __restrict__ gate_ptr,
    const float* __restrict__ g3, const float* __restrict__ b3,
    const float* __restrict__ g4, const float* __restrict__ b4,
    float* __restrict__ X, ushort_t* __restrict__ T1b){
  __shared__ float sh[256*33];
  __shared__ float red[8*32];
  __shared__ float rwsh[32];
  const float RSD = 0.022097086912079608f;
  int tid = threadIdx.x;
  size_t tok = blockIdx.x;
  const float* a = T0 + tok * DD;
  float v[8]; float s = 0.f, ss = 0.f;
  #pragma unroll
  for (int j = 0; j < 8; j++){
    int d = tid + 256*j;
    v[j] = a[d]; s += v[j]; ss += v[j]*v[j];
  }
  float mean = block_sum256(s) * (1.f/DD);
  float var  = block_sum256(ss) * (1.f/DD) - mean*mean;
  float inv  = rsqrtf(var + 1e-5f);
  float y2[8], xq[8];
  #pragma unroll
  for (int j = 0; j < 8; j++){
    int d = tid + 256*j;
    y2[j] = (v[j] - mean) * inv * g2[d] + b2[d];
    xq[j] = y2[j] * SQBi[d];
  }
  float aa[32];
  #pragma unroll 4
  for (int r = 0; r < 32; r++){
    float t = 0.f;
    #pragma unroll
    for (int j = 0; j < 8; j++)
      t = fmaf(xq[j], bf2f(RLSi[(size_t)r*DD + tid + 256*j]), t);
    aa[r] = t;
  }
  #pragma unroll
  for (int r = 0; r < 32; r++) sh[tid*33 + r] = aa[r];
  __syncthreads();
  {
    int r = tid & 31, gg = tid >> 5;
    float t = 0.f;
    #pragma unroll 8
    for (int i = 0; i < 32; i++) t += sh[(gg*32 + i)*33 + r];
    red[gg*32 + r] = t;
  }
  __syncthreads();
  if (tid < 32){
    float t = 0.f;
    #pragma unroll
    for (int gg = 0; gg < 8; gg++) t += red[gg*32 + tid];
    rwsh[tid] = sigm(4.f * RSD * t);
  }
  __syncthreads();
  float gate = sigm(*gate_ptr);
  float p3[8]; s = 0.f; ss = 0.f;
  #pragma unroll
  for (int j = 0; j < 8; j++){
    int d = tid + 256*j;
    float t = 0.f;
    #pragma unroll 8
    for (int r = 0; r < 32; r++)
      t = fmaf(rwsh[r], bf2f(RLSi[(size_t)r*DD + d]), t);
    float lo = y2[j] * t;
    p3[j] = y2[j] + gate * (lo - y2[j]);
    s += p3[j]; ss += p3[j]*p3[j];
  }
  mean = block_sum256(s) * (1.f/DD);
  var  = block_sum256(ss) * (1.f/DD) - mean*mean;
  inv  = rsqrtf(var + 1e-5f);
  float y3[8]; s = 0.f; ss = 0.f;
  #pragma unroll
  for (int j = 0; j < 8; j++){
    int d = tid + 256*j;
    y3[j] = (p3[j] - mean) * inv * g3[d] + b3[d];
    X[tok*DD + d] = y3[j];
    s += y3[j]; ss += y3[j]*y3[j];
  }
  mean = block_sum256(s) * (1.f/DD);
  var  = block_sum256(ss) * (1.f/DD) - mean*mean;
  inv  = rsqrtf(var + 1e-5f);
  #pragma unroll
  for (int j = 0; j < 8; j++){
    int d = tid + 256*j;
    T1b[tok*DD + d] = f2bf((y3[j] - mean) * inv * g4[d] + b4[d]);
  }
}

// Thought-loop glue: Hnew = (gate? H + sigm(*gate)*(Xr-H) : Xr); H=Hnew;
// y = LN(Hnew)*g+b (+pos) -> fp32 outX and/or bf16 outXb.
__global__ __launch_bounds__(256) void tl_kernel(const float* __restrict__ Xr,
    float* __restrict__ H, const float* __restrict__ gate_ptr,
    const float* __restrict__ g, const float* __restrict__ be,
    const float* __restrict__ pos,
    float* __restrict__ outX, ushort_t* __restrict__ outXb){
  size_t row = blockIdx.x;
  float gate = gate_ptr ? sigm(*gate_ptr) : 1.f;
  float v[8]; float s = 0.f, ss = 0.f;
  #pragma unroll
  for (int j = 0; j < 8; j++){
    int d = threadIdx.x + j*256;
    float xr = Xr[row*DD + d];
    float hv = gate_ptr ? H[row*DD + d] : 0.f;
    float hn = gate_ptr ? (hv + gate * (xr - hv)) : xr;
    H[row*DD + d] = hn;
    v[j] = hn; s += hn; ss += hn*hn;
  }
  float mean = block_sum256(s) * (1.f/DD);
  float var  = block_sum256(ss) * (1.f/DD) - mean*mean;
  float inv  = rsqrtf(var + 1e-5f);
  #pragma unroll
  for (int j = 0; j < 8; j++){
    int d = threadIdx.x + j*256;
    float y = (v[j] - mean) * inv * g[d] + be[d];
    if (pos) y += pos[d];
    if (outX)  outX[row*DD + d] = y;
    if (outXb) outXb[row*DD + d] = f2bf(y);
  }
}

// ===================== bf16 MFMA NT GEMM (+split-K, +bf16 mirror) =====================
template<int BM, int BN, int SPLITK, int ACT, bool CAUSAL, bool OUTBF>
__global__ __launch_bounds__(256) void gemm_nt(const ushort_t* __restrict__ A,
    const ushort_t* __restrict__ B, void* __restrict__ Cv,
    int K, int lda, int ldb, int ldc,
    long sA, long sB, long sC,
    const float* __restrict__ colscale, const float* __restrict__ bias,
    const float* __restrict__ res, ushort_t* __restrict__ mirror,
    const float* __restrict__ alpha_ptr, float alpha_c)
{
  constexpr int FM = BM / 32;
  constexpr int FN = BN / 32;
  __shared__ __align__(16) ushort_t shA[BM * 64];
  __shared__ __align__(16) ushort_t shB[BN * 64];
  const int tid = threadIdx.x;
  const int l = tid & 63, w = tid >> 6;
  const int wr = w >> 1, wc = w & 1;
  const int row0 = blockIdx.y * BM, col0 = blockIdx.x * BN;
  const int zb = blockIdx.z / SPLITK, zk = blockIdx.z % SPLITK;

  if (CAUSAL && col0 > row0 + BM - 1) return;  // reduce kernel masks these

  A += (size_t)zb * sA;
  B += (size_t)zb * sB;
  const int kbeg = zk * (K / SPLITK), kend = kbeg + K / SPLITK;

  f32x4 acc[FM][FN] = {};

  for (int kt = kbeg; kt < kend; kt += 64){
    #pragma unroll
    for (int i = 0; i < BM/32; i++){
      int o = i*4096 + tid*16;
      int r = o >> 7, c = (o >> 4) & 7;
      int lc = c ^ (r & 7);
      async_copy16((char*)shA + o, A + (size_t)(row0 + r) * lda + kt + lc*8);
    }
    #pragma unroll
    for (int i = 0; i < BN/32; i++){
      int o = i*4096 + tid*16;
      int r = o >> 7, c = (o >> 4) & 7;
      int lc = c ^ (r & 7);
      async_copy16((char*)shB + o, B + (size_t)(col0 + r) * ldb + kt + lc*8);
    }
    __syncthreads();
    #pragma unroll
    for (int kk = 0; kk < 2; kk++){
      s16x8 af[FM], bfr[FN];
      #pragma unroll
      for (int mi = 0; mi < FM; mi++){
        int r = wr*(BM/2) + mi*16 + (l & 15);
        int c = kk*4 + (l >> 4);
        af[mi] = *(const s16x8*)((const char*)shA + r*128 + (c ^ (r & 7))*16);
      }
      #pragma unroll
      for (int ni = 0; ni < FN; ni++){
        int r = wc*(BN/2) + ni*16 + (l & 15);
        int c = kk*4 + (l >> 4);
        bfr[ni] = *(const s16x8*)((const char*)shB + r*128 + (c ^ (r & 7))*16);
      }
      #pragma unroll
      for (int mi = 0; mi < FM; mi++)
        #pragma unroll
        for (int ni = 0; ni < FN; ni++)
          acc[mi][ni] = __builtin_amdgcn_mfma_f32_16x16x32_bf16(af[mi], bfr[ni], acc[mi][ni], 0, 0, 0);
    }
    __syncthreads();
  }

  if (SPLITK > 1){
    float* P = (float*)Cv + (size_t)blockIdx.z * sC;
    #pragma unroll
    for (int mi = 0; mi < FM; mi++)
      #pragma unroll
      for (int ni = 0; ni < FN; ni++)
        #pragma unroll
        for (int j = 0; j < 4; j++){
          int m = row0 + wr*(BM/2) + mi*16 + (l >> 4)*4 + j;
          int n = col0 + wc*(BN/2) + ni*16 + (l & 15);
          P[(size_t)m * ldc + n] = acc[mi][ni][j];
        }
    return;
  }

  float alpha = alpha_c * (alpha_ptr ? *alpha_ptr : 1.f);
  float* Cf = (float*)Cv + (size_t)zb * sC;
  ushort_t* Cb = (ushort_t*)Cv + (size_t)zb * sC;
  const float* resz = res ? res + (size_t)zb * sC : nullptr;
  #pragma unroll
  for (int mi = 0; mi < FM; mi++){
    #pragma unroll
    for (int ni = 0; ni < FN; ni++){
      #pragma unroll
      for (int j = 0; j < 4; j++){
        int m = row0 + wr*(BM/2) + mi*16 + (l >> 4)*4 + j;
        int n = col0 + wc*(BN/2) + ni*16 + (l & 15);
        float v = acc[mi][ni][j] * alpha;
        if (colscale) v *= colscale[n];
        if (bias) v += bias[n];
        if (ACT == 1) v = sigm(4.f * v);
        else if (ACT == 2) v = 0.5f * v * (1.f + erff(v * 0.70710678118654752f));
        if (CAUSAL && n > m) v = 0.f;
        if (resz) v += resz[(size_t)m * ldc + n];
        if (OUTBF) Cb[(size_t)m * ldc + n] = f2bf(v);
        else       Cf[(size_t)m * ldc + n] = v;
        if (mirror) mirror[(size_t)m * ldc + n] = f2bf(v);
      }
    }
  }
}

// ===================== bf16 MFMA NN GEMM (register-staged transposed B) =====================
// C[M,N] = A[M,K] . B[K,N] + res, fp32 out. Tiles 64x64, 4 waves (2x2).
// B tile is transposed into the SAME swizzled LDS layout the NT frag-read uses,
// via per-thread global loads + 8 scalar ds_write_b16 (conflict-free: lanes-along-k).
__global__ __launch_bounds__(256) void gemm_nn(const ushort_t* __restrict__ A,
    const ushort_t* __restrict__ B, float* __restrict__ C,
    int K, int lda, int ldb, int ldc,
    long sA, long sB, long sC,
    const float* __restrict__ res)
{
  __shared__ __align__(16) ushort_t shA[64 * 64];
  __shared__ __align__(16) ushort_t shB[64 * 64];
  const int tid = threadIdx.x;
  const int l = tid & 63, w = tid >> 6;
  const int wr = w >> 1, wc = w & 1;
  const int row0 = blockIdx.y * 64, col0 = blockIdx.x * 64;
  A += (size_t)blockIdx.z * sA;
  B += (size_t)blockIdx.z * sB;

  const int kb = tid & 63;          // k-row this thread stages
  const int nb0 = (tid >> 6) * 8;   // n-chunk start (+32 on second iter)

  f32x4 acc[2][2] = {};

  for (int kt = 0; kt < K; kt += 64){
    #pragma unroll
    for (int i = 0; i < 2; i++){
      int o = i*4096 + tid*16;
      int r = o >> 7, c = (o >> 4) & 7;
      int lc = c ^ (r & 7);
      async_copy16((char*)shA + o, A + (size_t)(row0 + r) * lda + kt + lc*8);
    }
    // B transpose-stage: load B[kt+kb][col0+n0..+8), scatter to shB[n][kb] (swizzled)
    #pragma unroll
    for (int i = 0; i < 2; i++){
      int n0 = nb0 + i*32;
      s16x8 v = *(const s16x8*)(B + (size_t)(kt + kb) * ldb + col0 + n0);
      #pragma unroll
      for (int j = 0; j < 8; j++){
        int n = n0 + j;
        int off = n*128 + (((kb >> 3) ^ (n & 7)) << 4) + ((kb & 7) << 1);
        *(ushort_t*)((char*)shB + off) = (ushort_t)v[j];
      }
    }
    __syncthreads();
    #pragma unroll
    for (int kk = 0; kk < 2; kk++){
      s16x8 af[2], bfr[2];
      #pragma unroll
      for (int mi = 0; mi < 2; mi++){
        int r = wr*32 + mi*16 + (l & 15);
        int c = kk*4 + (l >> 4);
        af[mi] = *(const s16x8*)((const char*)shA + r*128 + ((c ^ (r & 7)) << 4));
      }
      #pragma unroll
      for (int ni = 0; ni < 2; ni++){
        int r = wc*32 + ni*16 + (l & 15);
        int c = kk*4 + (l >> 4);
        bfr[ni] = *(const s16x8*)((const char*)shB + r*128 + ((c ^ (r & 7)) << 4));
      }
      #pragma unroll
      for (int mi = 0; mi < 2; mi++)
        #pragma unroll
        for (int ni = 0; ni < 2; ni++)
          acc[mi][ni] = __builtin_amdgcn_mfma_f32_16x16x32_bf16(af[mi], bfr[ni], acc[mi][ni], 0, 0, 0);
    }
    __syncthreads();
  }

  float* Cf = C + (size_t)blockIdx.z * sC;
  const float* resz = res ? res + (size_t)blockIdx.z * sC : nullptr;
  #pragma unroll
  for (int mi = 0; mi < 2; mi++)
    #pragma unroll
    for (int ni = 0; ni < 2; ni++)
      #pragma unroll
      for (int j = 0; j < 4; j++){
        int m = row0 + wr*32 + mi*16 + (l >> 4)*4 + j;
        int n = col0 + wc*32 + ni*16 + (l & 15);
        float v = acc[mi][ni][j];
        if (resz) v += resz[(size_t)m * ldc + n];
        Cf[(size_t)m * ldc + n] = v;
      }
}

// ===================== decoder: NT GEMM, A bf16 async, B fp32 reg-staged+cvt =====================
// C[M,N] = (A[M,K] . B[N,K]^T) * (*alpha_ptr), fp32 out. BM=256, BN=64, K%64==0.
__global__ __launch_bounds__(256) void gemm_ntf(const ushort_t* __restrict__ A,
    const float* __restrict__ B, float* __restrict__ C,
    int K, int lda, int ldb, int ldc,
    const float* __restrict__ alpha_ptr)
{
  constexpr int BM = 256, BN = 64, FM = 8, FN = 2;
  __shared__ __align__(16) ushort_t shA[BM * 64];
  __shared__ __align__(16) ushort_t shB[BN * 64];
  const int tid = threadIdx.x;
  const int l = tid & 63, w = tid >> 6;
  const int wr = w >> 1, wc = w & 1;
  const int row0 = blockIdx.y * BM, col0 = blockIdx.x * BN;

  f32x4 acc[FM][FN] = {};

  for (int kt = 0; kt < K; kt += 64){
    #pragma unroll
    for (int i = 0; i < BM/32; i++){
      int o = i*4096 + tid*16;
      int r = o >> 7, c = (o >> 4) & 7;
      int lc = c ^ (r & 7);
      async_copy16((char*)shA + o, A + (size_t)(row0 + r) * lda + kt + lc*8);
    }
    // B: 64 rows(n) x 64 k fp32 -> cvt bf16 -> swizzled shB
    #pragma unroll
    for (int i = 0; i < 4; i++){
      int c2 = tid + i*256;
      int r = c2 & 63, kq = c2 >> 6;          // kq in 0..15, 4 k-elems each
      float4 v = *(const float4*)(B + (size_t)(col0 + r) * ldb + kt + kq*4);
      u32 p0 = ((u32)f2bf(v.y) << 16) | (u32)f2bf(v.x);
      u32 p1 = ((u32)f2bf(v.w) << 16) | (u32)f2bf(v.z);
      int off = r*128 + (((kq >> 1) ^ (r & 7)) << 4) + ((kq & 1) << 3);
      uint2 pp; pp.x = p0; pp.y = p1;
      *(uint2*)((char*)shB + off) = pp;
    }
    __syncthreads();
    #pragma unroll
    for (int kk = 0; kk < 2; kk++){
      s16x8 af[FM], bfr[FN];
      #pragma unroll
      for (int mi = 0; mi < FM; mi++){
        int r = wr*(BM/2) + mi*16 + (l & 15);
        int c = kk*4 + (l >> 4);
        af[mi] = *(const s16x8*)((const char*)shA + r*128 + ((c ^ (r & 7)) << 4));
      }
      #pragma unroll
      for (int ni = 0; ni < FN; ni++){
        int r = wc*(BN/2) + ni*16 + (l & 15);
        int c = kk*4 + (l >> 4);
        bfr[ni] = *(const s16x8*)((const char*)shB + r*128 + ((c ^ (r & 7)) << 4));
      }
      #pragma unroll
      for (int mi = 0; mi < FM; mi++)
        #pragma unroll
        for (int ni = 0; ni < FN; ni++)
          acc[mi][ni] = __builtin_amdgcn_mfma_f32_16x16x32_bf16(af[mi], bfr[ni], acc[mi][ni], 0, 0, 0);
    }
    __syncthreads();
  }

  float alpha = *alpha_ptr;
  #pragma unroll
  for (int mi = 0; mi < FM; mi++)
    #pragma unroll
    for (int ni = 0; ni < FN; ni++)
      #pragma unroll
      for (int j = 0; j < 4; j++){
        int m = row0 + wr*(BM/2) + mi*16 + (l >> 4)*4 + j;
        int n = col0 + wc*(BN/2) + ni*16 + (l & 15);
        C[(size_t)m * ldc + n] = acc[mi][ni][j] * alpha;
      }
}

// split-K reduce + epilogue
template<int S, int ACT, bool CAUSAL, bool OUTBF>
__global__ __launch_bounds__(256) void reduce_epi(const float* __restrict__ P,
    void* __restrict__ outv, int M, int N, const float* __restrict__ bias, float alpha){
  long MN = (long)M * N;
  long idx = ((long)blockIdx.x * 256 + threadIdx.x) * 4;
  int b = (int)(idx / MN);
  long r = idx - (long)b * MN;
  int m = (int)(r / N), n = (int)(r % N);
  float vv[4] = {0.f, 0.f, 0.f, 0.f};
  #pragma unroll
  for (int s = 0; s < S; s++){
    float4 p = *(const float4*)&P[((long)(b*S + s)) * MN + r];
    vv[0] += p.x; vv[1] += p.y; vv[2] += p.z; vv[3] += p.w;
  }
  ushort4 ob; float4 of;
  float* po = (float*)&of;
  ushort_t* pb = (ushort_t*)&ob;
  #pragma unroll
  for (int j = 0; j < 4; j++){
    float v = vv[j] * alpha;
    if (bias) v += bias[n + j];
    if (ACT == 1) v = sigm(4.f * v);
    else if (ACT == 2) v = 0.5f * v * (1.f + erff(v * 0.70710678118654752f));
    if (CAUSAL && n + j > m) v = 0.f;
    po[j] = v; pb[j] = f2bf(v);
  }
  if (OUTBF) *(ushort4*)&((ushort_t*)outv)[(long)b*MN + r] = ob;
  else       *(float4*)&((float*)outv)[(long)b*MN + r] = of;
}

extern "C" void kernel_launch(void* const* d_in, const int* in_sizes, int n_in,
                              void* d_out, int out_size, void* d_ws, size_t ws_size,
                              hipStream_t stream){
  const int*   idx        = (const int*)  d_in[0];
  const float* cb         = (const float*)d_in[1];
  const float* decay_lg   = (const float*)d_in[2];
  const float* bv_q       = (const float*)d_in[3];
  const float* bv_k       = (const float*)d_in[4];
  const float* bv_v       = (const float*)d_in[5];
  const float* rules      = (const float*)d_in[6];
  const float* query_bind = (const float*)d_in[7];
  const float* logic_gate = (const float*)d_in[8];
  const float* ln_mem_g   = (const float*)d_in[9];
  const float* ln_mem_b   = (const float*)d_in[10];
  const float* ln_attn_g  = (const float*)d_in[11];
  const float* ln_attn_b  = (const float*)d_in[12];
  const float* ln_logic_g = (const float*)d_in[13];
  const float* ln_logic_b = (const float*)d_in[14];
  const float* ctrl_g     = (const float*)d_in[15];
  const float* ctrl_b     = (const float*)d_in[16];
  const float* down_w     = (const float*)d_in[17];
  const float* down_b     = (const float*)d_in[18];
  const float* up_w       = (const float*)d_in[19];
  const float* up_b       = (const float*)d_in[20];
  const float* tl_gates   = (const float*)d_in[21];
  const float* tl_pos     = (const float*)d_in[22];
  const float* tl_g       = (const float*)d_in[23];
  const float* tl_b       = (const float*)d_in[24];
  const float* out_g      = (const float*)d_in[25];
  const float* out_b      = (const float*)d_in[26];
  const float* oscale     = (const float*)d_in[27];
  float* out = (float*)d_out;

  const size_t ND = (size_t)NTOK * DD;
  char* p = (char*)d_ws;
  auto alloc = [&](size_t bytes){ void* r = p; p += (bytes + 255) & ~(size_t)255; return r; };
  float*    X       = (float*)   alloc(ND * 4);
  float*    H       = (float*)   alloc(ND * 4);
  float*    T0      = (float*)   alloc(ND * 4);
  ushort_t* Xrb     = (ushort_t*)alloc(ND * 2);
  ushort_t* Xb      = (ushort_t*)alloc(ND * 2);
  ushort_t* Xqb     = (ushort_t*)alloc(ND * 2);
  ushort_t* Xvb     = (ushort_t*)alloc(ND * 2);
  ushort_t* T1b     = (ushort_t*)alloc(ND * 2);
  ushort_t* ATTNb   = (ushort_t*)alloc((size_t)NBAT * TT * TT * 2);
  ushort_t* CBb     = (ushort_t*)alloc((size_t)NTOK * CC * 2);
  float*    PP      = (float*)   alloc((size_t)8 * NTOK * CC * 4);   // 8 MiB partials
  float*    SQK     = (float*)   alloc((size_t)NBLK * DD * 4);
  float*    SV      = (float*)   alloc((size_t)NBLK * DD * 4);
  float*    SQB     = (float*)   alloc((size_t)NBLK * DD * 4);
  ushort_t* RLSb    = (ushort_t*)alloc((size_t)NBLK * RR * DD * 2);
  ushort_t* Adec    = (ushort_t*)alloc((size_t)NBLK * TT * TT * 2);
  ushort_t* down_wb = (ushort_t*)alloc((size_t)NBLK * CC * DD * 2);
  ushort_t* up_wb   = (ushort_t*)alloc((size_t)NBLK * DD * CC * 2);
  // total ~48 MiB — well under the r3-proven workspace bound

  const float RSD = 0.022097086912079608f;  // D^-0.5

  // ---- one-time prep (4 dispatches) ----
  sign_prep_kernel<<<3*NBLK + NBLK*RR, 256, 0, stream>>>(
      bv_q, bv_k, bv_v, query_bind, rules, SQK, SV, SQB, RLSb);
  adec_kernel<<<dim3(TT, NBLK), 256, 0, stream>>>(decay_lg, Adec);
  cvt2_kernel<<<2048, 256, 0, stream>>>(down_w, down_wb, (long)NBLK*CC*DD/4,
                                        up_w, up_wb, (long)NBLK*DD*CC/4);
  encode_kernel<<<NTOK, 256, 0, stream>>>(idx, cb, X, Xrb);

  auto run_blocks = [&](){
    for (int i = 0; i < NBLK; i++){
      const size_t iD = (size_t)i * DD;
      // --- EMA as NN matmul: T0 = Adec_i @ Xrb + X ---
      gemm_nn<<<dim3(DD/64, TT/64, NBAT), 256, 0, stream>>>(
          Adec + (size_t)i*TT*TT, Xrb, T0, TT, TT, DD, DD,
          0, (long)TT*DD, (long)TT*DD, X);
      // --- LN_mem -> X (fp32), Xb, Xqb=y*SQK, Xvb=y*SV ---
      ln_kernel<<<NTOK, 256, 0, stream>>>(T0, ln_mem_g + iD, ln_mem_b + iD,
          X, Xb, SQK + iD, Xqb, SV + iD, Xvb);
      // --- scores (split-K 8) + reduce(sigmoid4, causal) -> ATTNb ---
      gemm_nt<64,64,8,0,true,false><<<dim3(TT/64, TT/64, NBAT*8), 256, 0, stream>>>(
          Xqb, Xb, PP, DD, DD, DD, TT,
          (long)TT*DD, (long)TT*DD, (long)TT*TT,
          nullptr, nullptr, nullptr, nullptr, nullptr, 1.f);
      reduce_epi<8,1,true,true><<<(NBAT*TT*TT)/1024, 256, 0, stream>>>(
          PP, ATTNb, TT, TT, nullptr, RSD);
      // --- att_out as NN matmul: T0 = ATTN @ Xvb + X ---
      gemm_nn<<<dim3(DD/64, TT/64, NBAT), 256, 0, stream>>>(
          ATTNb, Xvb, T0, TT, TT, DD, DD,
          (long)TT*TT, (long)TT*DD, (long)TT*DD, X);
      // --- mega-fused LN_attn + logic + gate + LN_logic + ctrl-LN ---
      fuse_logic_kernel<<<NTOK, 256, 0, stream>>>(T0,
          RLSb + (size_t)i*RR*DD, SQB + iD,
          ln_attn_g + iD, ln_attn_b + iD, logic_gate + i,
          ln_logic_g + iD, ln_logic_b + iD, ctrl_g + iD, ctrl_b + iD,
          X, T1b);
      // --- MLP down (split-K 8) + reduce(bias, gelu) -> CBb ---
      gemm_nt<64,64,8,0,false,false><<<dim3(CC/64, NTOK/64, 8), 256, 0, stream>>>(
          T1b, down_wb + (size_t)i*CC*DD, PP, DD, DD, DD, CC,
          0, 0, (long)NTOK*CC,
          nullptr, nullptr, nullptr, nullptr, nullptr, 1.f);
      reduce_epi<8,2,false,true><<<(NTOK*CC)/1024, 256, 0, stream>>>(
          PP, CBb, NTOK, CC, down_b + (size_t)i*CC, 1.f);
      // --- MLP up: X = CBb @ up_w^T + bias + X  (+ bf16 mirror Xrb) ---
      gemm_nt<64,64,1,0,false,false><<<dim3(DD/64, NTOK/64, 1), 256, 0, stream>>>(
          CBb, up_wb + (size_t)i*DD*CC, X, CC, CC, CC, DD,
          0, 0, 0, nullptr, up_b + iD, X, Xrb, nullptr, 1.f);
    }
  };

  run_blocks();
  // ti=1: H = X; X = LN(H)*tl_g+tl_b + pos[1]  (+Xrb mirror)
  tl_kernel<<<NTOK, 256, 0, stream>>>(X, H, nullptr, tl_g, tl_b,
      tl_pos + (size_t)1*DD, X, Xrb);
  run_blocks();
  // ti=2: H += s(g1)(X-H); X = LN(H) + pos[2]
  tl_kernel<<<NTOK, 256, 0, stream>>>(X, H, tl_gates + 1, tl_g, tl_b,
      tl_pos + (size_t)2*DD, X, Xrb);
  run_blocks();
  // final: H += s(g2)(X-H); T1b = bf16(LN(H)*out_g+out_b)
  tl_kernel<<<NTOK, 256, 0, stream>>>(X, H, tl_gates + 2, out_g, out_b,
      nullptr, nullptr, T1b);
  // logits = (LN(h) . cb^T) * output_scale  — B is fp32 codebook, staged+cvt in-kernel
  gemm_ntf<<<dim3(VV/64, NTOK/256, 1), 256, 0, stream>>>(
      T1b, cb, out, DD, DD, DD, VV, oscale);
}